// Round 3
// baseline (347.545 us; speedup 1.0000x reference)
//
#include <hip/hip_runtime.h>
#include <hip/hip_bf16.h>

#define Bn 2
#define Sn 1024
#define Dn 2048
#define Hn 16
#define HKVn 4
#define HDn 128

typedef __attribute__((ext_vector_type(8))) short s8v;
typedef __attribute__((ext_vector_type(8))) unsigned short u8v;
typedef __attribute__((ext_vector_type(4))) float f4v;
typedef __hip_bfloat16 bf16;

typedef __attribute__((address_space(3))) void lds_void;
typedef __attribute__((address_space(1))) const void gbl_void;
#define ASYNC_LD16(g, l) \
  __builtin_amdgcn_global_load_lds((gbl_void*)(g), (lds_void*)(l), 16, 0, 0)

static __device__ __forceinline__ unsigned short f2b_bits(float f) {
  bf16 h = __float2bfloat16(f);
  return __builtin_bit_cast(unsigned short, h);
}

// ---------------- mask normalize (detect int32 vs byte bool) ----------------
__global__ void mask_norm(const void* __restrict__ mraw, unsigned char* __restrict__ m8, int n) {
  __shared__ int bytemode;
  if (threadIdx.x == 0) bytemode = 0;
  __syncthreads();
  const unsigned int* mi = (const unsigned int*)mraw;
  int local = 0;
  for (int t = threadIdx.x; t < n / 4; t += blockDim.x)
    if (mi[t] > 1u) local = 1;
  if (local) atomicOr(&bytemode, 1);
  __syncthreads();
  const int bm = bytemode;
  const unsigned char* mb = (const unsigned char*)mraw;
  for (int t = threadIdx.x; t < n; t += blockDim.x)
    m8[t] = bm ? (mb[t] ? 1 : 0) : (mi[t] != 0u ? 1 : 0);
}

// ---------------- fp32 -> bf16 convert (16B stores) ----------------
__global__ void cvt_bf16(const float* __restrict__ src, bf16* __restrict__ dst, int n8) {
  int stride = gridDim.x * blockDim.x;
  for (int i = blockIdx.x * blockDim.x + threadIdx.x; i < n8; i += stride) {
    float4 a = reinterpret_cast<const float4*>(src)[2 * i];
    float4 b = reinterpret_cast<const float4*>(src)[2 * i + 1];
    u8v o;
    o[0] = f2b_bits(a.x); o[1] = f2b_bits(a.y); o[2] = f2b_bits(a.z); o[3] = f2b_bits(a.w);
    o[4] = f2b_bits(b.x); o[5] = f2b_bits(b.y); o[6] = f2b_bits(b.z); o[7] = f2b_bits(b.w);
    reinterpret_cast<u8v*>(dst)[i] = o;
  }
}

// ---------------- fp32 (K,N) -> bf16 (N,K) transpose, 64x64 tiles ----------------
__global__ __launch_bounds__(256) void transpose_w(const float* __restrict__ src,
                                                   bf16* __restrict__ dst, int K, int N) {
  __shared__ float tile[64][65];
  const int bx = blockIdx.x * 64;  // n
  const int by = blockIdx.y * 64;  // k
  const int t = threadIdx.x;
  const int lr = t >> 4, lc4 = (t & 15) * 4;
  #pragma unroll
  for (int it = 0; it < 4; ++it) {
    int k = it * 16 + lr;
    float4 v = *reinterpret_cast<const float4*>(&src[(size_t)(by + k) * N + bx + lc4]);
    tile[k][lc4] = v.x; tile[k][lc4 + 1] = v.y; tile[k][lc4 + 2] = v.z; tile[k][lc4 + 3] = v.w;
  }
  __syncthreads();
  #pragma unroll
  for (int it = 0; it < 4; ++it) {
    int n = it * 16 + lr;
    ushort4 o;
    o.x = f2b_bits(tile[lc4 + 0][n]);
    o.y = f2b_bits(tile[lc4 + 1][n]);
    o.z = f2b_bits(tile[lc4 + 2][n]);
    o.w = f2b_bits(tile[lc4 + 3][n]);
    *reinterpret_cast<ushort4*>(&dst[(size_t)(bx + n) * K + by + lc4]) = o;
  }
}

// ---------------- NT GEMM via global_load_lds: C[M,N] = A[M,K] * Bt[N,K]^T ----------------
// EPI 0: scatter to q (B,H,S,HD), k (B,HKV,S,HD), vT (B,HKV,HD,S)   (N=3072)
// EPI 1: write fp32 C row-major (N=2048)
template <int EPI>
__global__ __launch_bounds__(256) void gemm_nt(
    const bf16* __restrict__ A, const bf16* __restrict__ Bt,
    bf16* __restrict__ Oq, bf16* __restrict__ Ok, bf16* __restrict__ Ov,
    float* __restrict__ Of, int K, int N) {
  __shared__ __align__(16) bf16 Al[128 * 64];
  __shared__ __align__(16) bf16 Bl[128 * 64];
  const int tid = threadIdx.x;
  const int lane = tid & 63, w = tid >> 6;
  const int wm = (w >> 1) * 64, wn = (w & 1) * 64;
  const int m0 = blockIdx.y * 128, n0 = blockIdx.x * 128;
  const int l16 = lane & 15, lg = lane >> 4;
  const int srow = lane >> 3;        // 0..7 within 8-row chunk
  const int scol = (lane & 7) * 8;   // element offset within 64-wide row
  f4v acc[4][4] = {};
  for (int k0 = 0; k0 < K; k0 += 64) {
    #pragma unroll
    for (int ci = 0; ci < 4; ++ci) {
      const int rb = w * 32 + ci * 8;  // wave-uniform chunk base row
      ASYNC_LD16(&A[(size_t)(m0 + rb + srow) * K + k0 + scol], &Al[rb * 64]);
      ASYNC_LD16(&Bt[(size_t)(n0 + rb + srow) * K + k0 + scol], &Bl[rb * 64]);
    }
    __syncthreads();
    #pragma unroll
    for (int kc = 0; kc < 2; ++kc) {
      s8v af[4], bfr[4];
      #pragma unroll
      for (int mf = 0; mf < 4; ++mf)
        af[mf] = *reinterpret_cast<const s8v*>(&Al[(wm + mf * 16 + l16) * 64 + kc * 32 + lg * 8]);
      #pragma unroll
      for (int nf = 0; nf < 4; ++nf)
        bfr[nf] = *reinterpret_cast<const s8v*>(&Bl[(wn + nf * 16 + l16) * 64 + kc * 32 + lg * 8]);
      __builtin_amdgcn_s_setprio(1);
      #pragma unroll
      for (int mf = 0; mf < 4; ++mf)
        #pragma unroll
        for (int nf = 0; nf < 4; ++nf)
          acc[mf][nf] = __builtin_amdgcn_mfma_f32_16x16x32_bf16(af[mf], bfr[nf], acc[mf][nf], 0, 0, 0);
      __builtin_amdgcn_s_setprio(0);
    }
    __syncthreads();
  }
  #pragma unroll
  for (int mf = 0; mf < 4; ++mf) {
    #pragma unroll
    for (int nf = 0; nf < 4; ++nf) {
      #pragma unroll
      for (int i = 0; i < 4; ++i) {
        int gm = m0 + wm + mf * 16 + lg * 4 + i;
        int gn = n0 + wn + nf * 16 + l16;
        float v = acc[mf][nf][i];
        if (EPI == 0) {
          int b = gm >> 10, s = gm & 1023;
          if (gn < 2048) {
            int h = gn >> 7, hd = gn & 127;
            Oq[(((size_t)(b * Hn + h)) * Sn + s) * HDn + hd] = __float2bfloat16(v);
          } else if (gn < 2560) {
            int t = gn - 2048, kvh = t >> 7, hd = t & 127;
            Ok[(((size_t)(b * HKVn + kvh)) * Sn + s) * HDn + hd] = __float2bfloat16(v);
          } else {
            int t = gn - 2560, kvh = t >> 7, hd = t & 127;
            Ov[(((size_t)(b * HKVn + kvh)) * HDn + hd) * Sn + s] = __float2bfloat16(v);
          }
        } else {
          Of[(size_t)gm * N + gn] = v;
        }
      }
    }
  }
}

// ---------------- RoPE in-place, vectorized x4 ----------------
__global__ void rope_qk(bf16* __restrict__ qb, bf16* __restrict__ kb,
                        const float* __restrict__ cosp, const float* __restrict__ sinp) {
  const int NQ = Bn * Hn * Sn * 16;         // q quads (16 per row-half)
  const int NT = NQ + Bn * HKVn * Sn * 16;  // + k quads
  int stride = gridDim.x * blockDim.x;
  for (int idx = blockIdx.x * blockDim.x + threadIdx.x; idx < NT; idx += stride) {
    bf16* base;
    int rel;
    if (idx < NQ) { base = qb; rel = idx; }
    else          { base = kb; rel = idx - NQ; }
    int d4 = (rel & 15) * 4;
    int s = (rel >> 4) & 1023;
    int head = rel >> 14;
    bf16* p = base + ((size_t)head * Sn + s) * HDn + d4;
    ushort4 a = *reinterpret_cast<ushort4*>(p);
    ushort4 b = *reinterpret_cast<ushort4*>(p + 64);
    float4 c = *reinterpret_cast<const float4*>(&cosp[s * HDn + d4]);
    float4 sv = *reinterpret_cast<const float4*>(&sinp[s * HDn + d4]);
    float x1[4] = {__bfloat162float(__builtin_bit_cast(bf16, a.x)), __bfloat162float(__builtin_bit_cast(bf16, a.y)),
                   __bfloat162float(__builtin_bit_cast(bf16, a.z)), __bfloat162float(__builtin_bit_cast(bf16, a.w))};
    float x2[4] = {__bfloat162float(__builtin_bit_cast(bf16, b.x)), __bfloat162float(__builtin_bit_cast(bf16, b.y)),
                   __bfloat162float(__builtin_bit_cast(bf16, b.z)), __bfloat162float(__builtin_bit_cast(bf16, b.w))};
    float cc[4] = {c.x, c.y, c.z, c.w};
    float ss[4] = {sv.x, sv.y, sv.z, sv.w};
    ushort4 o1, o2;
    unsigned short* o1p = &o1.x; unsigned short* o2p = &o2.x;
    #pragma unroll
    for (int j = 0; j < 4; ++j) {
      o1p[j] = f2b_bits(x1[j] * cc[j] - x2[j] * ss[j]);
      o2p[j] = f2b_bits(x2[j] * cc[j] + x1[j] * ss[j]);
    }
    *reinterpret_cast<ushort4*>(p) = o1;
    *reinterpret_cast<ushort4*>(p + 64) = o2;
  }
}

// ---------------- fused flash attention (GQA, causal + active mask) ----------------
// grid: (S/64, H, B), block 256 (4 waves, 16 q-rows each)
__global__ __launch_bounds__(256) void attn_fwd(
    const bf16* __restrict__ q, const bf16* __restrict__ k, const bf16* __restrict__ vT,
    const unsigned char* __restrict__ m8, bf16* __restrict__ out) {
  __shared__ __align__(16) bf16 Pl[4][16 * 72];
  const int tid = threadIdx.x;
  const int lane = tid & 63, w = tid >> 6;
  const int l16 = lane & 15, lg = lane >> 4;
  const int qt = blockIdx.x, h = blockIdx.y, b = blockIdx.z;
  const int hkv = h >> 2;
  const int q0 = qt * 64 + w * 16;
  const float sl2 = 0.08838834764831845f * 1.44269504088896f;  // scale * log2(e)

  const bf16* qp = q + ((size_t)(b * Hn + h) * Sn + q0) * HDn;
  const bf16* kp = k + (size_t)(b * HKVn + hkv) * Sn * HDn;
  const bf16* vp = vT + (size_t)(b * HKVn + hkv) * HDn * Sn;
  const unsigned char* mp = m8 + b * Sn;

  s8v qf[4];
  #pragma unroll
  for (int hc = 0; hc < 4; ++hc)
    qf[hc] = *reinterpret_cast<const s8v*>(qp + l16 * HDn + hc * 32 + lg * 8);

  float mrow[4], lrow[4];
  f4v o[8] = {};
  #pragma unroll
  for (int i = 0; i < 4; ++i) { mrow[i] = -1e30f; lrow[i] = 0.f; }

  for (int kt = 0; kt <= qt; ++kt) {
    const int kb = kt * 64;
    f4v sc[4] = {};
    #pragma unroll
    for (int ktc = 0; ktc < 4; ++ktc) {
      s8v kf0 = *reinterpret_cast<const s8v*>(kp + (size_t)(kb + ktc * 16 + l16) * HDn + 0 * 32 + lg * 8);
      s8v kf1 = *reinterpret_cast<const s8v*>(kp + (size_t)(kb + ktc * 16 + l16) * HDn + 1 * 32 + lg * 8);
      s8v kf2 = *reinterpret_cast<const s8v*>(kp + (size_t)(kb + ktc * 16 + l16) * HDn + 2 * 32 + lg * 8);
      s8v kf3 = *reinterpret_cast<const s8v*>(kp + (size_t)(kb + ktc * 16 + l16) * HDn + 3 * 32 + lg * 8);
      __builtin_amdgcn_s_setprio(1);
      sc[ktc] = __builtin_amdgcn_mfma_f32_16x16x32_bf16(qf[0], kf0, sc[ktc], 0, 0, 0);
      sc[ktc] = __builtin_amdgcn_mfma_f32_16x16x32_bf16(qf[1], kf1, sc[ktc], 0, 0, 0);
      sc[ktc] = __builtin_amdgcn_mfma_f32_16x16x32_bf16(qf[2], kf2, sc[ktc], 0, 0, 0);
      sc[ktc] = __builtin_amdgcn_mfma_f32_16x16x32_bf16(qf[3], kf3, sc[ktc], 0, 0, 0);
      __builtin_amdgcn_s_setprio(0);
    }
    // mask + scale(log2e) + per-row max (rows in (lg, reg i); cols in l16 x 4 tiles)
    float pm[4];
    #pragma unroll
    for (int i = 0; i < 4; ++i) pm[i] = -1e30f;
    int act[4];
    #pragma unroll
    for (int ktc = 0; ktc < 4; ++ktc) act[ktc] = mp[kb + ktc * 16 + l16];
    #pragma unroll
    for (int ktc = 0; ktc < 4; ++ktc) {
      int j = kb + ktc * 16 + l16;
      #pragma unroll
      for (int i = 0; i < 4; ++i) {
        int qr = q0 + lg * 4 + i;
        float v = sc[ktc][i] * sl2;
        v = (act[ktc] && j <= qr) ? v : -1e30f;
        sc[ktc][i] = v;
        pm[i] = fmaxf(pm[i], v);
      }
    }
    #pragma unroll
    for (int off = 1; off < 16; off <<= 1)
      #pragma unroll
      for (int i = 0; i < 4; ++i) pm[i] = fmaxf(pm[i], __shfl_xor(pm[i], off, 64));
    float fac[4];
    #pragma unroll
    for (int i = 0; i < 4; ++i) {
      float mn = fmaxf(mrow[i], pm[i]);
      fac[i] = exp2f(mrow[i] - mn);
      mrow[i] = mn;
    }
    float rs[4] = {0.f, 0.f, 0.f, 0.f};
    #pragma unroll
    for (int ktc = 0; ktc < 4; ++ktc)
      #pragma unroll
      for (int i = 0; i < 4; ++i) {
        float p = exp2f(sc[ktc][i] - mrow[i]);
        rs[i] += p;
        Pl[w][(lg * 4 + i) * 72 + ktc * 16 + l16] = __float2bfloat16(p);
      }
    #pragma unroll
    for (int off = 1; off < 16; off <<= 1)
      #pragma unroll
      for (int i = 0; i < 4; ++i) rs[i] += __shfl_xor(rs[i], off, 64);
    #pragma unroll
    for (int i = 0; i < 4; ++i) lrow[i] = lrow[i] * fac[i] + rs[i];
    #pragma unroll
    for (int fn = 0; fn < 8; ++fn)
      #pragma unroll
      for (int i = 0; i < 4; ++i) o[fn][i] *= fac[i];
    // PV
    #pragma unroll
    for (int kc = 0; kc < 2; ++kc) {
      s8v pf = *reinterpret_cast<const s8v*>(&Pl[w][l16 * 72 + kc * 32 + lg * 8]);
      __builtin_amdgcn_s_setprio(1);
      #pragma unroll
      for (int fn = 0; fn < 8; ++fn) {
        s8v vf = *reinterpret_cast<const s8v*>(vp + (size_t)(fn * 16 + l16) * Sn + kb + kc * 32 + lg * 8);
        o[fn] = __builtin_amdgcn_mfma_f32_16x16x32_bf16(pf, vf, o[fn], 0, 0, 0);
      }
      __builtin_amdgcn_s_setprio(0);
    }
  }
  // write attn_out (B*S, H*HD) bf16
  #pragma unroll
  for (int fn = 0; fn < 8; ++fn)
    #pragma unroll
    for (int i = 0; i < 4; ++i) {
      int qr = q0 + lg * 4 + i;
      out[((size_t)b * Sn + qr) * (Hn * HDn) + h * HDn + fn * 16 + l16] =
          __float2bfloat16(o[fn][i] / lrow[i]);
    }
}

extern "C" void kernel_launch(void* const* d_in, const int* in_sizes, int n_in,
                              void* d_out, int out_size, void* d_ws, size_t ws_size,
                              hipStream_t stream) {
  const float* hs   = (const float*)d_in[0];
  const float* cosp = (const float*)d_in[1];
  const float* sinp = (const float*)d_in[2];
  const float* wq   = (const float*)d_in[3];
  const float* wk   = (const float*)d_in[4];
  const float* wv   = (const float*)d_in[5];
  const float* wo   = (const float*)d_in[6];
  const void*  am   = d_in[8];   // position_ids (d_in[7]) == arange, unused

  char* ws = (char*)d_ws;
  bf16* WT  = (bf16*)(ws);                         // (3072, 2048) bf16 = 12.58 MB
  bf16* woT = (bf16*)(ws + 12582912);              // (2048, 2048) bf16 = 8 MB
  bf16* qb  = (bf16*)(ws + 12582912 + 8388608);    // (B,H,S,HD)  8 MB
  bf16* kb  = (bf16*)(ws + 12582912 + 16777216);   // (B,HKV,S,HD) 2 MB
  bf16* vT  = (bf16*)(ws + 12582912 + 18874368);   // (B,HKV,HD,S) 2 MB
  bf16* ao  = (bf16*)(ws + 12582912 + 20971520);   // (B*S, 2048)  8 MB
  unsigned char* m8 = (unsigned char*)(ws + 12582912 + 29360128);
  bf16* hsb = (bf16*)d_out;                        // scratch: hs bf16 (8 MB of 16 MB out buf)
  float* outp = (float*)d_out;

  mask_norm<<<1, 256, 0, stream>>>(am, m8, Bn * Sn);
  cvt_bf16<<<2048, 256, 0, stream>>>(hs, hsb, (Bn * Sn * Dn) / 8);
  transpose_w<<<dim3(32, 32), 256, 0, stream>>>(wq, WT, Dn, 2048);
  transpose_w<<<dim3(8, 32), 256, 0, stream>>>(wk, WT + (size_t)2048 * Dn, Dn, 512);
  transpose_w<<<dim3(8, 32), 256, 0, stream>>>(wv, WT + (size_t)2560 * Dn, Dn, 512);
  transpose_w<<<dim3(32, 32), 256, 0, stream>>>(wo, woT, Dn, 2048);
  gemm_nt<0><<<dim3(24, 16), 256, 0, stream>>>(hsb, WT, qb, kb, vT, nullptr, Dn, 3072);
  rope_qk<<<1024, 256, 0, stream>>>(qb, kb, cosp, sinp);
  attn_fwd<<<dim3(Sn / 64, Hn, Bn), 256, 0, stream>>>(qb, kb, vT, m8, ao);
  gemm_nt<1><<<dim3(16, 16), 256, 0, stream>>>(ao, woT, nullptr, nullptr, nullptr, outp, Hn * HDn, Dn);
}

// Round 4
// 254.504 us; speedup vs baseline: 1.3656x; 1.3656x over previous
//
#include <hip/hip_runtime.h>
#include <hip/hip_bf16.h>

#define Bn 2
#define Sn 1024
#define Dn 2048
#define Hn 16
#define HKVn 4
#define HDn 128

typedef __attribute__((ext_vector_type(8))) short s8v;
typedef __attribute__((ext_vector_type(8))) unsigned short u8v;
typedef __attribute__((ext_vector_type(4))) float f4v;
typedef __hip_bfloat16 bf16;

typedef __attribute__((address_space(3))) void lds_void;
typedef __attribute__((address_space(1))) const void gbl_void;
#define ASYNC_LD16(g, l) \
  __builtin_amdgcn_global_load_lds((gbl_void*)(g), (lds_void*)(l), 16, 0, 0)

static __device__ __forceinline__ unsigned short f2b_bits(float f) {
  bf16 h = __float2bfloat16(f);
  return __builtin_bit_cast(unsigned short, h);
}

// ---------------- mask normalize (detect int32 vs byte bool) ----------------
__global__ void mask_norm(const void* __restrict__ mraw, unsigned char* __restrict__ m8, int n) {
  __shared__ int bytemode;
  if (threadIdx.x == 0) bytemode = 0;
  __syncthreads();
  const unsigned int* mi = (const unsigned int*)mraw;
  int local = 0;
  for (int t = threadIdx.x; t < n / 4; t += blockDim.x)
    if (mi[t] > 1u) local = 1;
  if (local) atomicOr(&bytemode, 1);
  __syncthreads();
  const int bm = bytemode;
  const unsigned char* mb = (const unsigned char*)mraw;
  for (int t = threadIdx.x; t < n; t += blockDim.x)
    m8[t] = bm ? (mb[t] ? 1 : 0) : (mi[t] != 0u ? 1 : 0);
}

// ---------------- fp32 -> bf16 convert (16B stores) ----------------
__global__ void cvt_bf16(const float* __restrict__ src, bf16* __restrict__ dst, int n8) {
  int stride = gridDim.x * blockDim.x;
  for (int i = blockIdx.x * blockDim.x + threadIdx.x; i < n8; i += stride) {
    float4 a = reinterpret_cast<const float4*>(src)[2 * i];
    float4 b = reinterpret_cast<const float4*>(src)[2 * i + 1];
    u8v o;
    o[0] = f2b_bits(a.x); o[1] = f2b_bits(a.y); o[2] = f2b_bits(a.z); o[3] = f2b_bits(a.w);
    o[4] = f2b_bits(b.x); o[5] = f2b_bits(b.y); o[6] = f2b_bits(b.z); o[7] = f2b_bits(b.w);
    reinterpret_cast<u8v*>(dst)[i] = o;
  }
}

// ---------------- fp32 (K,N) -> bf16 (N,K) transpose, 64x64 tiles ----------------
__global__ __launch_bounds__(256) void transpose_w(const float* __restrict__ src,
                                                   bf16* __restrict__ dst, int K, int N) {
  __shared__ float tile[64][65];
  const int bx = blockIdx.x * 64;  // n
  const int by = blockIdx.y * 64;  // k
  const int t = threadIdx.x;
  const int lr = t >> 4, lc4 = (t & 15) * 4;
  #pragma unroll
  for (int it = 0; it < 4; ++it) {
    int k = it * 16 + lr;
    float4 v = *reinterpret_cast<const float4*>(&src[(size_t)(by + k) * N + bx + lc4]);
    tile[k][lc4] = v.x; tile[k][lc4 + 1] = v.y; tile[k][lc4 + 2] = v.z; tile[k][lc4 + 3] = v.w;
  }
  __syncthreads();
  #pragma unroll
  for (int it = 0; it < 4; ++it) {
    int n = it * 16 + lr;
    ushort4 o;
    o.x = f2b_bits(tile[lc4 + 0][n]);
    o.y = f2b_bits(tile[lc4 + 1][n]);
    o.z = f2b_bits(tile[lc4 + 2][n]);
    o.w = f2b_bits(tile[lc4 + 3][n]);
    *reinterpret_cast<ushort4*>(&dst[(size_t)(bx + n) * K + by + lc4]) = o;
  }
}

// ---------------- NT GEMM (round-1 proven): C[M,N] = A[M,K](bf16) * Bt[N,K]^T ----------------
template <int EPI>
__global__ __launch_bounds__(256) void gemm_nt(
    const bf16* __restrict__ A, const bf16* __restrict__ Bt,
    bf16* __restrict__ Oq, bf16* __restrict__ Ok, bf16* __restrict__ Ov,
    float* __restrict__ Of, int K, int N) {
  __shared__ __align__(16) bf16 Al[128 * 72];
  __shared__ __align__(16) bf16 Bl[128 * 72];
  const int tid = threadIdx.x;
  const int lane = tid & 63, w = tid >> 6;
  const int wm = (w >> 1) * 64, wn = (w & 1) * 64;
  const int m0 = blockIdx.y * 128, n0 = blockIdx.x * 128;
  const int lr = tid >> 3, lc = (tid & 7) * 8;
  const int l16 = lane & 15, lg = lane >> 4;
  f4v acc[4][4] = {};
  for (int k0 = 0; k0 < K; k0 += 64) {
    #pragma unroll
    for (int p = 0; p < 4; ++p) {
      int r = lr + p * 32;
      *reinterpret_cast<float4*>(&Al[r * 72 + lc]) =
          *reinterpret_cast<const float4*>(&A[(size_t)(m0 + r) * K + k0 + lc]);
      *reinterpret_cast<float4*>(&Bl[r * 72 + lc]) =
          *reinterpret_cast<const float4*>(&Bt[(size_t)(n0 + r) * K + k0 + lc]);
    }
    __syncthreads();
    #pragma unroll
    for (int kc = 0; kc < 2; ++kc) {
      s8v af[4], bfr[4];
      #pragma unroll
      for (int mf = 0; mf < 4; ++mf)
        af[mf] = *reinterpret_cast<const s8v*>(&Al[(wm + mf * 16 + l16) * 72 + kc * 32 + lg * 8]);
      #pragma unroll
      for (int nf = 0; nf < 4; ++nf)
        bfr[nf] = *reinterpret_cast<const s8v*>(&Bl[(wn + nf * 16 + l16) * 72 + kc * 32 + lg * 8]);
      #pragma unroll
      for (int mf = 0; mf < 4; ++mf)
        #pragma unroll
        for (int nf = 0; nf < 4; ++nf)
          acc[mf][nf] = __builtin_amdgcn_mfma_f32_16x16x32_bf16(af[mf], bfr[nf], acc[mf][nf], 0, 0, 0);
    }
    __syncthreads();
  }
  #pragma unroll
  for (int mf = 0; mf < 4; ++mf) {
    #pragma unroll
    for (int nf = 0; nf < 4; ++nf) {
      #pragma unroll
      for (int i = 0; i < 4; ++i) {
        int gm = m0 + wm + mf * 16 + lg * 4 + i;
        int gn = n0 + wn + nf * 16 + l16;
        float v = acc[mf][nf][i];
        if (EPI == 0) {
          int b = gm >> 10, s = gm & 1023;
          if (gn < 2048) {
            int h = gn >> 7, hd = gn & 127;
            Oq[(((size_t)(b * Hn + h)) * Sn + s) * HDn + hd] = __float2bfloat16(v);
          } else if (gn < 2560) {
            int t = gn - 2048, kvh = t >> 7, hd = t & 127;
            Ok[(((size_t)(b * HKVn + kvh)) * Sn + s) * HDn + hd] = __float2bfloat16(v);
          } else {
            int t = gn - 2560, kvh = t >> 7, hd = t & 127;
            Ov[(((size_t)(b * HKVn + kvh)) * HDn + hd) * Sn + s] = __float2bfloat16(v);
          }
        } else {
          Of[(size_t)gm * N + gn] = v;
        }
      }
    }
  }
}

// ---------------- RoPE in-place, vectorized x4 ----------------
__global__ void rope_qk(bf16* __restrict__ qb, bf16* __restrict__ kb,
                        const float* __restrict__ cosp, const float* __restrict__ sinp) {
  const int NQ = Bn * Hn * Sn * 16;
  const int NT = NQ + Bn * HKVn * Sn * 16;
  int stride = gridDim.x * blockDim.x;
  for (int idx = blockIdx.x * blockDim.x + threadIdx.x; idx < NT; idx += stride) {
    bf16* base;
    int rel;
    if (idx < NQ) { base = qb; rel = idx; }
    else          { base = kb; rel = idx - NQ; }
    int d4 = (rel & 15) * 4;
    int s = (rel >> 4) & 1023;
    int head = rel >> 14;
    bf16* p = base + ((size_t)head * Sn + s) * HDn + d4;
    ushort4 a = *reinterpret_cast<ushort4*>(p);
    ushort4 b = *reinterpret_cast<ushort4*>(p + 64);
    float4 c = *reinterpret_cast<const float4*>(&cosp[s * HDn + d4]);
    float4 sv = *reinterpret_cast<const float4*>(&sinp[s * HDn + d4]);
    float x1[4] = {__bfloat162float(__builtin_bit_cast(bf16, a.x)), __bfloat162float(__builtin_bit_cast(bf16, a.y)),
                   __bfloat162float(__builtin_bit_cast(bf16, a.z)), __bfloat162float(__builtin_bit_cast(bf16, a.w))};
    float x2[4] = {__bfloat162float(__builtin_bit_cast(bf16, b.x)), __bfloat162float(__builtin_bit_cast(bf16, b.y)),
                   __bfloat162float(__builtin_bit_cast(bf16, b.z)), __bfloat162float(__builtin_bit_cast(bf16, b.w))};
    float cc[4] = {c.x, c.y, c.z, c.w};
    float ss[4] = {sv.x, sv.y, sv.z, sv.w};
    ushort4 o1, o2;
    unsigned short* o1p = &o1.x; unsigned short* o2p = &o2.x;
    #pragma unroll
    for (int j = 0; j < 4; ++j) {
      o1p[j] = f2b_bits(x1[j] * cc[j] - x2[j] * ss[j]);
      o2p[j] = f2b_bits(x2[j] * cc[j] + x1[j] * ss[j]);
    }
    *reinterpret_cast<ushort4*>(p) = o1;
    *reinterpret_cast<ushort4*>(p + 64) = o2;
  }
}

// ---------------- fused flash attention, LDS-staged K/V (swizzled), 2-phase dbuf ----------------
// grid: (S/64, H, B), block 256 (4 waves, 16 q-rows each)
// K tile [64][128] bf16: 16 chunks(16B)/row, chunk' = chunk ^ (row&7)
// V tile [128][64] bf16 (from vT [HD][S]): 8 chunks/row, chunk' = chunk ^ (row&7)
__global__ __launch_bounds__(256) void attn_fwd(
    const bf16* __restrict__ q, const bf16* __restrict__ k, const bf16* __restrict__ vT,
    const unsigned char* __restrict__ m8, bf16* __restrict__ out) {
  __shared__ __align__(16) bf16 Kl[2][64 * 128];
  __shared__ __align__(16) bf16 Vl[2][128 * 64];
  __shared__ __align__(16) bf16 Pl[4][16 * 72];
  const int tid = threadIdx.x;
  const int lane = tid & 63, w = tid >> 6;
  const int l16 = lane & 15, lg = lane >> 4;
  const int qx = blockIdx.x, h = blockIdx.y, b = blockIdx.z;
  const int NQT = Sn / 64;
  const int qt = (b == 1) ? (NQT - 1 - qx) : qx;   // balance co-resident pairs
  const int hkv = h >> 2;
  const int q0 = qt * 64 + w * 16;
  const float sl2 = 0.08838834764831845f * 1.44269504088896f;  // scale * log2(e)

  const bf16* qp = q + ((size_t)(b * Hn + h) * Sn + q0) * HDn;
  const bf16* kp = k + (size_t)(b * HKVn + hkv) * Sn * HDn;
  const bf16* vp = vT + (size_t)(b * HKVn + hkv) * HDn * Sn;
  const unsigned char* mp = m8 + b * Sn;

  // staging lane->chunk geometry (per wave-issue, 64 consecutive chunks)
  // K: ci = i*256 + w*64 + lane; row = ci>>4, ch = ci&15
  // V: same ci; row = ci>>3, ch = ci&7
  auto stage = [&](int buf, int kbase) {
    #pragma unroll
    for (int i = 0; i < 4; ++i) {
      int ci = i * 256 + w * 64 + lane;
      int kr = ci >> 4, kch = ci & 15;
      ASYNC_LD16(kp + (size_t)(kbase + kr) * HDn + ((kch ^ (kr & 7)) * 8),
                 &Kl[buf][(i * 256 + w * 64) * 8]);
      int vr = ci >> 3, vch = ci & 7;
      ASYNC_LD16(vp + (size_t)vr * Sn + kbase + ((vch ^ (vr & 7)) * 8),
                 &Vl[buf][(i * 256 + w * 64) * 8]);
    }
  };

  s8v qf[4];
  #pragma unroll
  for (int hc = 0; hc < 4; ++hc)
    qf[hc] = *reinterpret_cast<const s8v*>(qp + l16 * HDn + hc * 32 + lg * 8);

  float mrow[4], lrow[4];
  f4v o[8] = {};
  #pragma unroll
  for (int i = 0; i < 4; ++i) { mrow[i] = -1e30f; lrow[i] = 0.f; }

  stage(0, 0);
  __syncthreads();

  for (int kt = 0; kt <= qt; ++kt) {
    const int cur = kt & 1;
    const int kb = kt * 64;
    if (kt < qt) stage(cur ^ 1, kb + 64);

    f4v sc[4] = {};
    #pragma unroll
    for (int ktc = 0; ktc < 4; ++ktc) {
      #pragma unroll
      for (int hc = 0; hc < 4; ++hc) {
        int r = ktc * 16 + l16;
        s8v kf = *reinterpret_cast<const s8v*>(
            &Kl[cur][r * 128 + (((hc * 4 + lg) ^ (r & 7)) * 8)]);
        sc[ktc] = __builtin_amdgcn_mfma_f32_16x16x32_bf16(qf[hc], kf, sc[ktc], 0, 0, 0);
      }
    }
    // mask + scale(log2e) + per-row max
    float pm[4];
    #pragma unroll
    for (int i = 0; i < 4; ++i) pm[i] = -1e30f;
    int act[4];
    #pragma unroll
    for (int ktc = 0; ktc < 4; ++ktc) act[ktc] = mp[kb + ktc * 16 + l16];
    if (kt == qt) {
      #pragma unroll
      for (int ktc = 0; ktc < 4; ++ktc) {
        int j = kb + ktc * 16 + l16;
        #pragma unroll
        for (int i = 0; i < 4; ++i) {
          int qr = q0 + lg * 4 + i;
          float v = sc[ktc][i] * sl2;
          v = (act[ktc] && j <= qr) ? v : -1e30f;
          sc[ktc][i] = v;
          pm[i] = fmaxf(pm[i], v);
        }
      }
    } else {
      #pragma unroll
      for (int ktc = 0; ktc < 4; ++ktc) {
        #pragma unroll
        for (int i = 0; i < 4; ++i) {
          float v = sc[ktc][i] * sl2;
          v = act[ktc] ? v : -1e30f;
          sc[ktc][i] = v;
          pm[i] = fmaxf(pm[i], v);
        }
      }
    }
    #pragma unroll
    for (int off = 1; off < 16; off <<= 1)
      #pragma unroll
      for (int i = 0; i < 4; ++i) pm[i] = fmaxf(pm[i], __shfl_xor(pm[i], off, 64));
    float fac[4];
    #pragma unroll
    for (int i = 0; i < 4; ++i) {
      float mn = fmaxf(mrow[i], pm[i]);
      fac[i] = exp2f(mrow[i] - mn);
      mrow[i] = mn;
    }
    float rs[4] = {0.f, 0.f, 0.f, 0.f};
    #pragma unroll
    for (int ktc = 0; ktc < 4; ++ktc)
      #pragma unroll
      for (int i = 0; i < 4; ++i) {
        float p = exp2f(sc[ktc][i] - mrow[i]);
        rs[i] += p;
        Pl[w][(lg * 4 + i) * 72 + ktc * 16 + l16] = __float2bfloat16(p);
      }
    #pragma unroll
    for (int off = 1; off < 16; off <<= 1)
      #pragma unroll
      for (int i = 0; i < 4; ++i) rs[i] += __shfl_xor(rs[i], off, 64);
    #pragma unroll
    for (int i = 0; i < 4; ++i) lrow[i] = lrow[i] * fac[i] + rs[i];
    #pragma unroll
    for (int fn = 0; fn < 8; ++fn)
      #pragma unroll
      for (int i = 0; i < 4; ++i) o[fn][i] *= fac[i];
    // PV: A = P (16 rows x 32k), B = V rows (HD dim)
    #pragma unroll
    for (int kc = 0; kc < 2; ++kc) {
      s8v pf = *reinterpret_cast<const s8v*>(&Pl[w][l16 * 72 + kc * 32 + lg * 8]);
      #pragma unroll
      for (int fn = 0; fn < 8; ++fn) {
        int d = fn * 16 + l16;
        s8v vf = *reinterpret_cast<const s8v*>(
            &Vl[cur][d * 64 + (((kc * 4 + lg) ^ (d & 7)) * 8)]);
        o[fn] = __builtin_amdgcn_mfma_f32_16x16x32_bf16(pf, vf, o[fn], 0, 0, 0);
      }
    }
    __syncthreads();  // drains staged loads (vmcnt 0) + protects buffers
  }
  // write attn_out (B*S, H*HD) bf16
  #pragma unroll
  for (int fn = 0; fn < 8; ++fn)
    #pragma unroll
    for (int i = 0; i < 4; ++i) {
      int qr = q0 + lg * 4 + i;
      out[((size_t)b * Sn + qr) * (Hn * HDn) + h * HDn + fn * 16 + l16] =
          __float2bfloat16(o[fn][i] / lrow[i]);
    }
}

extern "C" void kernel_launch(void* const* d_in, const int* in_sizes, int n_in,
                              void* d_out, int out_size, void* d_ws, size_t ws_size,
                              hipStream_t stream) {
  const float* hs   = (const float*)d_in[0];
  const float* cosp = (const float*)d_in[1];
  const float* sinp = (const float*)d_in[2];
  const float* wq   = (const float*)d_in[3];
  const float* wk   = (const float*)d_in[4];
  const float* wv   = (const float*)d_in[5];
  const float* wo   = (const float*)d_in[6];
  const void*  am   = d_in[8];

  char* ws = (char*)d_ws;
  bf16* WT  = (bf16*)(ws);
  bf16* woT = (bf16*)(ws + 12582912);
  bf16* qb  = (bf16*)(ws + 12582912 + 8388608);
  bf16* kb  = (bf16*)(ws + 12582912 + 16777216);
  bf16* vT  = (bf16*)(ws + 12582912 + 18874368);
  bf16* ao  = (bf16*)(ws + 12582912 + 20971520);
  unsigned char* m8 = (unsigned char*)(ws + 12582912 + 29360128);
  bf16* hsb = (bf16*)d_out;
  float* outp = (float*)d_out;

  mask_norm<<<1, 256, 0, stream>>>(am, m8, Bn * Sn);
  cvt_bf16<<<2048, 256, 0, stream>>>(hs, hsb, (Bn * Sn * Dn) / 8);
  transpose_w<<<dim3(32, 32), 256, 0, stream>>>(wq, WT, Dn, 2048);
  transpose_w<<<dim3(8, 32), 256, 0, stream>>>(wk, WT + (size_t)2048 * Dn, Dn, 512);
  transpose_w<<<dim3(8, 32), 256, 0, stream>>>(wv, WT + (size_t)2560 * Dn, Dn, 512);
  transpose_w<<<dim3(32, 32), 256, 0, stream>>>(wo, woT, Dn, 2048);
  gemm_nt<0><<<dim3(24, 16), 256, 0, stream>>>(hsb, WT, qb, kb, vT, nullptr, Dn, 3072);
  rope_qk<<<1024, 256, 0, stream>>>(qb, kb, cosp, sinp);
  attn_fwd<<<dim3(Sn / 64, Hn, Bn), 256, 0, stream>>>(qb, kb, vT, m8, ao);
  gemm_nt<1><<<dim3(16, 16), 256, 0, stream>>>(ao, woT, nullptr, nullptr, nullptr, outp, Hn * HDn, Dn);
}

// Round 5
// 246.829 us; speedup vs baseline: 1.4080x; 1.0311x over previous
//
#include <hip/hip_runtime.h>
#include <hip/hip_bf16.h>

#define Bn 2
#define Sn 1024
#define Dn 2048
#define Hn 16
#define HKVn 4
#define HDn 128

typedef __attribute__((ext_vector_type(8))) short s8v;
typedef __attribute__((ext_vector_type(8))) unsigned short u8v;
typedef __attribute__((ext_vector_type(4))) float f4v;
typedef __hip_bfloat16 bf16;

typedef __attribute__((address_space(3))) void lds_void;
typedef __attribute__((address_space(1))) const void gbl_void;
#define ASYNC_LD16(g, l) \
  __builtin_amdgcn_global_load_lds((gbl_void*)(g), (lds_void*)(l), 16, 0, 0)

static __device__ __forceinline__ unsigned short f2b_bits(float f) {
  bf16 h = __float2bfloat16(f);
  return __builtin_bit_cast(unsigned short, h);
}

// ---------------- mask normalize (detect int32 vs byte bool) ----------------
__global__ void mask_norm(const void* __restrict__ mraw, unsigned char* __restrict__ m8, int n) {
  __shared__ int bytemode;
  if (threadIdx.x == 0) bytemode = 0;
  __syncthreads();
  const unsigned int* mi = (const unsigned int*)mraw;
  int local = 0;
  for (int t = threadIdx.x; t < n / 4; t += blockDim.x)
    if (mi[t] > 1u) local = 1;
  if (local) atomicOr(&bytemode, 1);
  __syncthreads();
  const int bm = bytemode;
  const unsigned char* mb = (const unsigned char*)mraw;
  for (int t = threadIdx.x; t < n; t += blockDim.x)
    m8[t] = bm ? (mb[t] ? 1 : 0) : (mi[t] != 0u ? 1 : 0);
}

// ---------------- fp32 -> bf16 convert (16B stores) ----------------
__global__ void cvt_bf16(const float* __restrict__ src, bf16* __restrict__ dst, int n8) {
  int stride = gridDim.x * blockDim.x;
  for (int i = blockIdx.x * blockDim.x + threadIdx.x; i < n8; i += stride) {
    float4 a = reinterpret_cast<const float4*>(src)[2 * i];
    float4 b = reinterpret_cast<const float4*>(src)[2 * i + 1];
    u8v o;
    o[0] = f2b_bits(a.x); o[1] = f2b_bits(a.y); o[2] = f2b_bits(a.z); o[3] = f2b_bits(a.w);
    o[4] = f2b_bits(b.x); o[5] = f2b_bits(b.y); o[6] = f2b_bits(b.z); o[7] = f2b_bits(b.w);
    reinterpret_cast<u8v*>(dst)[i] = o;
  }
}

// ---------------- fp32 (K,N) -> bf16 (N,K) transpose, 64x64 tiles, 4 jobs in z ----------------
__global__ __launch_bounds__(256) void transpose_all(
    const float* __restrict__ s0, const float* __restrict__ s1,
    const float* __restrict__ s2, const float* __restrict__ s3,
    bf16* __restrict__ d0, bf16* __restrict__ d1, bf16* __restrict__ d2, bf16* __restrict__ d3) {
  __shared__ float tile[64][65];
  const int z = blockIdx.z;
  const float* src = (z == 0) ? s0 : (z == 1) ? s1 : (z == 2) ? s2 : s3;
  bf16* dst = (z == 0) ? d0 : (z == 1) ? d1 : (z == 2) ? d2 : d3;
  const int N = (z == 1 || z == 2) ? 512 : 2048;
  const int K = Dn;
  const int bx = blockIdx.x * 64;  // n
  if (bx >= N) return;
  const int by = blockIdx.y * 64;  // k
  const int t = threadIdx.x;
  const int lr = t >> 4, lc4 = (t & 15) * 4;
  #pragma unroll
  for (int it = 0; it < 4; ++it) {
    int k = it * 16 + lr;
    float4 v = *reinterpret_cast<const float4*>(&src[(size_t)(by + k) * N + bx + lc4]);
    tile[k][lc4] = v.x; tile[k][lc4 + 1] = v.y; tile[k][lc4 + 2] = v.z; tile[k][lc4 + 3] = v.w;
  }
  __syncthreads();
  #pragma unroll
  for (int it = 0; it < 4; ++it) {
    int n = it * 16 + lr;
    ushort4 o;
    o.x = f2b_bits(tile[lc4 + 0][n]);
    o.y = f2b_bits(tile[lc4 + 1][n]);
    o.z = f2b_bits(tile[lc4 + 2][n]);
    o.w = f2b_bits(tile[lc4 + 3][n]);
    *reinterpret_cast<ushort4*>(&dst[(size_t)(bx + n) * K + by + lc4]) = o;
  }
}

// ---------------- NT GEMM, m97-style: global_load_lds + both-sides XOR swizzle ----------------
// Tile [128 rows][64 k] bf16 per operand: 8 chunks(16B)/row, chunk' = chunk ^ (row&7).
// EPI 0: scatter to q (B,H,S,HD), k (B,HKV,S,HD), vT (B,HKV,HD,S)   (N=3072)
// EPI 1: write fp32 C row-major (N=2048)
template <int EPI>
__global__ __launch_bounds__(256) void gemm_nt(
    const bf16* __restrict__ A, const bf16* __restrict__ Bt,
    bf16* __restrict__ Oq, bf16* __restrict__ Ok, bf16* __restrict__ Ov,
    float* __restrict__ Of, int K, int N) {
  __shared__ __align__(16) bf16 Al[128 * 64];
  __shared__ __align__(16) bf16 Bl[128 * 64];
  const int tid = threadIdx.x;
  const int lane = tid & 63, w = tid >> 6;
  const int wm = (w >> 1) * 64, wn = (w & 1) * 64;
  const int m0 = blockIdx.y * 128, n0 = blockIdx.x * 128;
  const int l16 = lane & 15, lg = lane >> 4;
  const int srow = lane >> 3;        // 0..7 row within 8-row chunk group
  const int sch = lane & 7;          // chunk within row
  f4v acc[4][4] = {};
  for (int k0 = 0; k0 < K; k0 += 64) {
    #pragma unroll
    for (int i = 0; i < 4; ++i) {
      const int rb = w * 32 + i * 8;          // wave-uniform base row
      const int r = rb + srow;
      const int cs = (sch ^ (r & 7)) * 8;     // pre-swizzled source column (elements)
      ASYNC_LD16(&A[(size_t)(m0 + r) * K + k0 + cs], &Al[rb * 64]);
      ASYNC_LD16(&Bt[(size_t)(n0 + r) * K + k0 + cs], &Bl[rb * 64]);
    }
    __syncthreads();
    #pragma unroll
    for (int kc = 0; kc < 2; ++kc) {
      s8v af[4], bfr[4];
      #pragma unroll
      for (int mf = 0; mf < 4; ++mf) {
        int r = wm + mf * 16 + l16;
        af[mf] = *reinterpret_cast<const s8v*>(&Al[r * 64 + (((kc * 4 + lg) ^ (r & 7)) * 8)]);
      }
      #pragma unroll
      for (int nf = 0; nf < 4; ++nf) {
        int r = wn + nf * 16 + l16;
        bfr[nf] = *reinterpret_cast<const s8v*>(&Bl[r * 64 + (((kc * 4 + lg) ^ (r & 7)) * 8)]);
      }
      #pragma unroll
      for (int mf = 0; mf < 4; ++mf)
        #pragma unroll
        for (int nf = 0; nf < 4; ++nf)
          acc[mf][nf] = __builtin_amdgcn_mfma_f32_16x16x32_bf16(af[mf], bfr[nf], acc[mf][nf], 0, 0, 0);
    }
    __syncthreads();
  }
  #pragma unroll
  for (int mf = 0; mf < 4; ++mf) {
    #pragma unroll
    for (int nf = 0; nf < 4; ++nf) {
      #pragma unroll
      for (int i = 0; i < 4; ++i) {
        int gm = m0 + wm + mf * 16 + lg * 4 + i;
        int gn = n0 + wn + nf * 16 + l16;
        float v = acc[mf][nf][i];
        if (EPI == 0) {
          int b = gm >> 10, s = gm & 1023;
          if (gn < 2048) {
            int h = gn >> 7, hd = gn & 127;
            Oq[(((size_t)(b * Hn + h)) * Sn + s) * HDn + hd] = __float2bfloat16(v);
          } else if (gn < 2560) {
            int t = gn - 2048, kvh = t >> 7, hd = t & 127;
            Ok[(((size_t)(b * HKVn + kvh)) * Sn + s) * HDn + hd] = __float2bfloat16(v);
          } else {
            int t = gn - 2560, kvh = t >> 7, hd = t & 127;
            Ov[(((size_t)(b * HKVn + kvh)) * HDn + hd) * Sn + s] = __float2bfloat16(v);
          }
        } else {
          Of[(size_t)gm * N + gn] = v;
        }
      }
    }
  }
}

// ---------------- RoPE in-place, vectorized x4 ----------------
__global__ void rope_qk(bf16* __restrict__ qb, bf16* __restrict__ kb,
                        const float* __restrict__ cosp, const float* __restrict__ sinp) {
  const int NQ = Bn * Hn * Sn * 16;
  const int NT = NQ + Bn * HKVn * Sn * 16;
  int stride = gridDim.x * blockDim.x;
  for (int idx = blockIdx.x * blockDim.x + threadIdx.x; idx < NT; idx += stride) {
    bf16* base;
    int rel;
    if (idx < NQ) { base = qb; rel = idx; }
    else          { base = kb; rel = idx - NQ; }
    int d4 = (rel & 15) * 4;
    int s = (rel >> 4) & 1023;
    int head = rel >> 14;
    bf16* p = base + ((size_t)head * Sn + s) * HDn + d4;
    ushort4 a = *reinterpret_cast<ushort4*>(p);
    ushort4 b = *reinterpret_cast<ushort4*>(p + 64);
    float4 c = *reinterpret_cast<const float4*>(&cosp[s * HDn + d4]);
    float4 sv = *reinterpret_cast<const float4*>(&sinp[s * HDn + d4]);
    float x1[4] = {__bfloat162float(__builtin_bit_cast(bf16, a.x)), __bfloat162float(__builtin_bit_cast(bf16, a.y)),
                   __bfloat162float(__builtin_bit_cast(bf16, a.z)), __bfloat162float(__builtin_bit_cast(bf16, a.w))};
    float x2[4] = {__bfloat162float(__builtin_bit_cast(bf16, b.x)), __bfloat162float(__builtin_bit_cast(bf16, b.y)),
                   __bfloat162float(__builtin_bit_cast(bf16, b.z)), __bfloat162float(__builtin_bit_cast(bf16, b.w))};
    float cc[4] = {c.x, c.y, c.z, c.w};
    float ss[4] = {sv.x, sv.y, sv.z, sv.w};
    ushort4 o1, o2;
    unsigned short* o1p = &o1.x; unsigned short* o2p = &o2.x;
    #pragma unroll
    for (int j = 0; j < 4; ++j) {
      o1p[j] = f2b_bits(x1[j] * cc[j] - x2[j] * ss[j]);
      o2p[j] = f2b_bits(x2[j] * cc[j] + x1[j] * ss[j]);
    }
    *reinterpret_cast<ushort4*>(p) = o1;
    *reinterpret_cast<ushort4*>(p + 64) = o2;
  }
}

// ---------------- fused flash attention, LDS-staged K/V (swizzled), 2-phase dbuf ----------------
__global__ __launch_bounds__(256) void attn_fwd(
    const bf16* __restrict__ q, const bf16* __restrict__ k, const bf16* __restrict__ vT,
    const unsigned char* __restrict__ m8, bf16* __restrict__ out) {
  __shared__ __align__(16) bf16 Kl[2][64 * 128];
  __shared__ __align__(16) bf16 Vl[2][128 * 64];
  __shared__ __align__(16) bf16 Pl[4][16 * 72];
  const int tid = threadIdx.x;
  const int lane = tid & 63, w = tid >> 6;
  const int l16 = lane & 15, lg = lane >> 4;
  const int qx = blockIdx.x, h = blockIdx.y, b = blockIdx.z;
  const int NQT = Sn / 64;
  const int qt = (b == 1) ? (NQT - 1 - qx) : qx;
  const int hkv = h >> 2;
  const int q0 = qt * 64 + w * 16;
  const float sl2 = 0.08838834764831845f * 1.44269504088896f;

  const bf16* qp = q + ((size_t)(b * Hn + h) * Sn + q0) * HDn;
  const bf16* kp = k + (size_t)(b * HKVn + hkv) * Sn * HDn;
  const bf16* vp = vT + (size_t)(b * HKVn + hkv) * HDn * Sn;
  const unsigned char* mp = m8 + b * Sn;

  auto stage = [&](int buf, int kbase) {
    #pragma unroll
    for (int i = 0; i < 4; ++i) {
      int ci = i * 256 + w * 64 + lane;
      int kr = ci >> 4, kch = ci & 15;
      ASYNC_LD16(kp + (size_t)(kbase + kr) * HDn + ((kch ^ (kr & 7)) * 8),
                 &Kl[buf][(i * 256 + w * 64) * 8]);
      int vr = ci >> 3, vch = ci & 7;
      ASYNC_LD16(vp + (size_t)vr * Sn + kbase + ((vch ^ (vr & 7)) * 8),
                 &Vl[buf][(i * 256 + w * 64) * 8]);
    }
  };

  s8v qf[4];
  #pragma unroll
  for (int hc = 0; hc < 4; ++hc)
    qf[hc] = *reinterpret_cast<const s8v*>(qp + l16 * HDn + hc * 32 + lg * 8);

  float mrow[4], lrow[4];
  f4v o[8] = {};
  #pragma unroll
  for (int i = 0; i < 4; ++i) { mrow[i] = -1e30f; lrow[i] = 0.f; }

  stage(0, 0);
  __syncthreads();

  for (int kt = 0; kt <= qt; ++kt) {
    const int cur = kt & 1;
    const int kb = kt * 64;
    if (kt < qt) stage(cur ^ 1, kb + 64);

    f4v sc[4] = {};
    #pragma unroll
    for (int ktc = 0; ktc < 4; ++ktc) {
      #pragma unroll
      for (int hc = 0; hc < 4; ++hc) {
        int r = ktc * 16 + l16;
        s8v kf = *reinterpret_cast<const s8v*>(
            &Kl[cur][r * 128 + (((hc * 4 + lg) ^ (r & 7)) * 8)]);
        sc[ktc] = __builtin_amdgcn_mfma_f32_16x16x32_bf16(qf[hc], kf, sc[ktc], 0, 0, 0);
      }
    }
    float pm[4];
    #pragma unroll
    for (int i = 0; i < 4; ++i) pm[i] = -1e30f;
    int act[4];
    #pragma unroll
    for (int ktc = 0; ktc < 4; ++ktc) act[ktc] = mp[kb + ktc * 16 + l16];
    if (kt == qt) {
      #pragma unroll
      for (int ktc = 0; ktc < 4; ++ktc) {
        int j = kb + ktc * 16 + l16;
        #pragma unroll
        for (int i = 0; i < 4; ++i) {
          int qr = q0 + lg * 4 + i;
          float v = sc[ktc][i] * sl2;
          v = (act[ktc] && j <= qr) ? v : -1e30f;
          sc[ktc][i] = v;
          pm[i] = fmaxf(pm[i], v);
        }
      }
    } else {
      #pragma unroll
      for (int ktc = 0; ktc < 4; ++ktc) {
        #pragma unroll
        for (int i = 0; i < 4; ++i) {
          float v = sc[ktc][i] * sl2;
          v = act[ktc] ? v : -1e30f;
          sc[ktc][i] = v;
          pm[i] = fmaxf(pm[i], v);
        }
      }
    }
    #pragma unroll
    for (int off = 1; off < 16; off <<= 1)
      #pragma unroll
      for (int i = 0; i < 4; ++i) pm[i] = fmaxf(pm[i], __shfl_xor(pm[i], off, 64));
    float fac[4];
    #pragma unroll
    for (int i = 0; i < 4; ++i) {
      float mn = fmaxf(mrow[i], pm[i]);
      fac[i] = exp2f(mrow[i] - mn);
      mrow[i] = mn;
    }
    float rs[4] = {0.f, 0.f, 0.f, 0.f};
    #pragma unroll
    for (int ktc = 0; ktc < 4; ++ktc)
      #pragma unroll
      for (int i = 0; i < 4; ++i) {
        float p = exp2f(sc[ktc][i] - mrow[i]);
        rs[i] += p;
        Pl[w][(lg * 4 + i) * 72 + ktc * 16 + l16] = __float2bfloat16(p);
      }
    #pragma unroll
    for (int off = 1; off < 16; off <<= 1)
      #pragma unroll
      for (int i = 0; i < 4; ++i) rs[i] += __shfl_xor(rs[i], off, 64);
    #pragma unroll
    for (int i = 0; i < 4; ++i) lrow[i] = lrow[i] * fac[i] + rs[i];
    #pragma unroll
    for (int fn = 0; fn < 8; ++fn)
      #pragma unroll
      for (int i = 0; i < 4; ++i) o[fn][i] *= fac[i];
    #pragma unroll
    for (int kc = 0; kc < 2; ++kc) {
      s8v pf = *reinterpret_cast<const s8v*>(&Pl[w][l16 * 72 + kc * 32 + lg * 8]);
      #pragma unroll
      for (int fn = 0; fn < 8; ++fn) {
        int d = fn * 16 + l16;
        s8v vf = *reinterpret_cast<const s8v*>(
            &Vl[cur][d * 64 + (((kc * 4 + lg) ^ (d & 7)) * 8)]);
        o[fn] = __builtin_amdgcn_mfma_f32_16x16x32_bf16(pf, vf, o[fn], 0, 0, 0);
      }
    }
    __syncthreads();
  }
  #pragma unroll
  for (int fn = 0; fn < 8; ++fn)
    #pragma unroll
    for (int i = 0; i < 4; ++i) {
      int qr = q0 + lg * 4 + i;
      out[((size_t)b * Sn + qr) * (Hn * HDn) + h * HDn + fn * 16 + l16] =
          __float2bfloat16(o[fn][i] / lrow[i]);
    }
}

extern "C" void kernel_launch(void* const* d_in, const int* in_sizes, int n_in,
                              void* d_out, int out_size, void* d_ws, size_t ws_size,
                              hipStream_t stream) {
  const float* hs   = (const float*)d_in[0];
  const float* cosp = (const float*)d_in[1];
  const float* sinp = (const float*)d_in[2];
  const float* wq   = (const float*)d_in[3];
  const float* wk   = (const float*)d_in[4];
  const float* wv   = (const float*)d_in[5];
  const float* wo   = (const float*)d_in[6];
  const void*  am   = d_in[8];

  char* ws = (char*)d_ws;
  bf16* WT  = (bf16*)(ws);
  bf16* woT = (bf16*)(ws + 12582912);
  bf16* qb  = (bf16*)(ws + 12582912 + 8388608);
  bf16* kb  = (bf16*)(ws + 12582912 + 16777216);
  bf16* vT  = (bf16*)(ws + 12582912 + 18874368);
  bf16* ao  = (bf16*)(ws + 12582912 + 20971520);
  unsigned char* m8 = (unsigned char*)(ws + 12582912 + 29360128);
  bf16* hsb = (bf16*)d_out;
  float* outp = (float*)d_out;

  mask_norm<<<1, 256, 0, stream>>>(am, m8, Bn * Sn);
  cvt_bf16<<<2048, 256, 0, stream>>>(hs, hsb, (Bn * Sn * Dn) / 8);
  transpose_all<<<dim3(32, 32, 4), 256, 0, stream>>>(
      wq, wk, wv, wo, WT, WT + (size_t)2048 * Dn, WT + (size_t)2560 * Dn, woT);
  gemm_nt<0><<<dim3(24, 16), 256, 0, stream>>>(hsb, WT, qb, kb, vT, nullptr, Dn, 3072);
  rope_qk<<<1024, 256, 0, stream>>>(qb, kb, cosp, sinp);
  attn_fwd<<<dim3(Sn / 64, Hn, Bn), 256, 0, stream>>>(qb, kb, vT, m8, ao);
  gemm_nt<1><<<dim3(16, 16), 256, 0, stream>>>(ao, woT, nullptr, nullptr, nullptr, outp, Hn * HDn, Dn);
}

// Round 8
// 238.108 us; speedup vs baseline: 1.4596x; 1.0366x over previous
//
#include <hip/hip_runtime.h>
#include <hip/hip_bf16.h>

#define Bn 2
#define Sn 1024
#define Dn 2048
#define Hn 16
#define HKVn 4
#define HDn 128

typedef __attribute__((ext_vector_type(8))) short s8v;
typedef __attribute__((ext_vector_type(8))) unsigned short u8v;
typedef __attribute__((ext_vector_type(4))) float f4v;
typedef __hip_bfloat16 bf16;

typedef __attribute__((address_space(3))) void lds_void;
typedef __attribute__((address_space(1))) const void gbl_void;
#define ASYNC_LD16(g, l) \
  __builtin_amdgcn_global_load_lds((gbl_void*)(g), (lds_void*)(l), 16, 0, 0)

static __device__ __forceinline__ unsigned short f2b_bits(float f) {
  bf16 h = __float2bfloat16(f);
  return __builtin_bit_cast(unsigned short, h);
}

// ---------------- mask normalize (detect int32 vs byte bool) ----------------
__global__ void mask_norm(const void* __restrict__ mraw, unsigned char* __restrict__ m8, int n) {
  __shared__ int bytemode;
  if (threadIdx.x == 0) bytemode = 0;
  __syncthreads();
  const unsigned int* mi = (const unsigned int*)mraw;
  int local = 0;
  for (int t = threadIdx.x; t < n / 4; t += blockDim.x)
    if (mi[t] > 1u) local = 1;
  if (local) atomicOr(&bytemode, 1);
  __syncthreads();
  const int bm = bytemode;
  const unsigned char* mb = (const unsigned char*)mraw;
  for (int t = threadIdx.x; t < n; t += blockDim.x)
    m8[t] = bm ? (mb[t] ? 1 : 0) : (mi[t] != 0u ? 1 : 0);
}

// ---------------- fp32 -> bf16 convert (16B stores) ----------------
__global__ void cvt_bf16(const float* __restrict__ src, bf16* __restrict__ dst, int n8) {
  int stride = gridDim.x * blockDim.x;
  for (int i = blockIdx.x * blockDim.x + threadIdx.x; i < n8; i += stride) {
    float4 a = reinterpret_cast<const float4*>(src)[2 * i];
    float4 b = reinterpret_cast<const float4*>(src)[2 * i + 1];
    u8v o;
    o[0] = f2b_bits(a.x); o[1] = f2b_bits(a.y); o[2] = f2b_bits(a.z); o[3] = f2b_bits(a.w);
    o[4] = f2b_bits(b.x); o[5] = f2b_bits(b.y); o[6] = f2b_bits(b.z); o[7] = f2b_bits(b.w);
    reinterpret_cast<u8v*>(dst)[i] = o;
  }
}

// ---------------- fp32 (K,N) -> bf16 (N,K) transpose, 64x64 tiles, 4 jobs in z ----------------
__global__ __launch_bounds__(256) void transpose_all(
    const float* __restrict__ s0, const float* __restrict__ s1,
    const float* __restrict__ s2, const float* __restrict__ s3,
    bf16* __restrict__ d0, bf16* __restrict__ d1, bf16* __restrict__ d2, bf16* __restrict__ d3) {
  __shared__ float tile[64][65];
  const int z = blockIdx.z;
  const float* src = (z == 0) ? s0 : (z == 1) ? s1 : (z == 2) ? s2 : s3;
  bf16* dst = (z == 0) ? d0 : (z == 1) ? d1 : (z == 2) ? d2 : d3;
  const int N = (z == 1 || z == 2) ? 512 : 2048;
  const int K = Dn;
  const int bx = blockIdx.x * 64;  // n
  if (bx >= N) return;
  const int by = blockIdx.y * 64;  // k
  const int t = threadIdx.x;
  const int lr = t >> 4, lc4 = (t & 15) * 4;
  #pragma unroll
  for (int it = 0; it < 4; ++it) {
    int k = it * 16 + lr;
    float4 v = *reinterpret_cast<const float4*>(&src[(size_t)(by + k) * N + bx + lc4]);
    tile[k][lc4] = v.x; tile[k][lc4 + 1] = v.y; tile[k][lc4 + 2] = v.z; tile[k][lc4 + 3] = v.w;
  }
  __syncthreads();
  #pragma unroll
  for (int it = 0; it < 4; ++it) {
    int n = it * 16 + lr;
    ushort4 o;
    o.x = f2b_bits(tile[lc4 + 0][n]);
    o.y = f2b_bits(tile[lc4 + 1][n]);
    o.z = f2b_bits(tile[lc4 + 2][n]);
    o.w = f2b_bits(tile[lc4 + 3][n]);
    *reinterpret_cast<ushort4*>(&dst[(size_t)(bx + n) * K + by + lc4]) = o;
  }
}

// ---------------- NT GEMM: global_load_lds + XOR swizzle + 2-phase double buffer ----------------
// Tile [128 rows][64 k] bf16 per operand: 8 chunks(16B)/row, chunk' = chunk ^ (row&7).
// 1D grid with bijective XCD swizzle (gridDim.x % 8 == 0).
// EPI 0: scatter to q (B,H,S,HD), k (B,HKV,S,HD), vT (B,HKV,HD,S)
// EPI 1: write fp32 C row-major
template <int EPI>
__global__ __launch_bounds__(256) void gemm_nt(
    const bf16* __restrict__ A, const bf16* __restrict__ Bt,
    bf16* __restrict__ Oq, bf16* __restrict__ Ok, bf16* __restrict__ Ov,
    float* __restrict__ Of, int K, int N, int nbx) {
  __shared__ __align__(16) bf16 Al[2][128 * 64];
  __shared__ __align__(16) bf16 Bl[2][128 * 64];
  const int tid = threadIdx.x;
  const int lane = tid & 63, w = tid >> 6;
  const int wm = (w >> 1) * 64, wn = (w & 1) * 64;
  const int nwg = gridDim.x;
  const int flat = blockIdx.x;
  const int swz = (flat & 7) * (nwg >> 3) + (flat >> 3);
  const int m0 = (swz / nbx) * 128, n0 = (swz % nbx) * 128;
  const int l16 = lane & 15, lg = lane >> 4;
  const int srow = lane >> 3;        // 0..7 row within 8-row chunk group
  const int sch = lane & 7;          // chunk within row
  f4v acc[4][4] = {};
  const int nt = K >> 6;

  auto stage = [&](int buf, int k0) {
    #pragma unroll
    for (int i = 0; i < 4; ++i) {
      const int rb = w * 32 + i * 8;          // wave-uniform base row
      const int r = rb + srow;
      const int cs = (sch ^ (r & 7)) * 8;     // pre-swizzled source column
      ASYNC_LD16(&A[(size_t)(m0 + r) * K + k0 + cs], &Al[buf][rb * 64]);
      ASYNC_LD16(&Bt[(size_t)(n0 + r) * K + k0 + cs], &Bl[buf][rb * 64]);
    }
  };

  stage(0, 0);
  __syncthreads();  // implicit vmcnt(0) drain

  for (int t = 0; t < nt; ++t) {
    const int cur = t & 1;
    if (t + 1 < nt) stage(cur ^ 1, (t + 1) << 6);  // prefetch overlaps compute
    #pragma unroll
    for (int kc = 0; kc < 2; ++kc) {
      s8v af[4], bfr[4];
      #pragma unroll
      for (int mf = 0; mf < 4; ++mf) {
        int r = wm + mf * 16 + l16;
        af[mf] = *reinterpret_cast<const s8v*>(&Al[cur][r * 64 + (((kc * 4 + lg) ^ (r & 7)) * 8)]);
      }
      #pragma unroll
      for (int nf = 0; nf < 4; ++nf) {
        int r = wn + nf * 16 + l16;
        bfr[nf] = *reinterpret_cast<const s8v*>(&Bl[cur][r * 64 + (((kc * 4 + lg) ^ (r & 7)) * 8)]);
      }
      #pragma unroll
      for (int mf = 0; mf < 4; ++mf)
        #pragma unroll
        for (int nf = 0; nf < 4; ++nf)
          acc[mf][nf] = __builtin_amdgcn_mfma_f32_16x16x32_bf16(af[mf], bfr[nf], acc[mf][nf], 0, 0, 0);
    }
    __syncthreads();  // drains prefetch (vmcnt 0) + protects both buffers
  }
  #pragma unroll
  for (int mf = 0; mf < 4; ++mf) {
    #pragma unroll
    for (int nf = 0; nf < 4; ++nf) {
      #pragma unroll
      for (int i = 0; i < 4; ++i) {
        int gm = m0 + wm + mf * 16 + lg * 4 + i;
        int gn = n0 + wn + nf * 16 + l16;
        float v = acc[mf][nf][i];
        if (EPI == 0) {
          int b = gm >> 10, s = gm & 1023;
          if (gn < 2048) {
            int h = gn >> 7, hd = gn & 127;
            Oq[(((size_t)(b * Hn + h)) * Sn + s) * HDn + hd] = __float2bfloat16(v);
          } else if (gn < 2560) {
            int t2 = gn - 2048, kvh = t2 >> 7, hd = t2 & 127;
            Ok[(((size_t)(b * HKVn + kvh)) * Sn + s) * HDn + hd] = __float2bfloat16(v);
          } else {
            int t2 = gn - 2560, kvh = t2 >> 7, hd = t2 & 127;
            Ov[(((size_t)(b * HKVn + kvh)) * HDn + hd) * Sn + s] = __float2bfloat16(v);
          }
        } else {
          Of[(size_t)gm * N + gn] = v;
        }
      }
    }
  }
}

// ---------------- RoPE in-place, vectorized x4 ----------------
__global__ void rope_qk(bf16* __restrict__ qb, bf16* __restrict__ kb,
                        const float* __restrict__ cosp, const float* __restrict__ sinp) {
  const int NQ = Bn * Hn * Sn * 16;
  const int NT = NQ + Bn * HKVn * Sn * 16;
  int stride = gridDim.x * blockDim.x;
  for (int idx = blockIdx.x * blockDim.x + threadIdx.x; idx < NT; idx += stride) {
    bf16* base;
    int rel;
    if (idx < NQ) { base = qb; rel = idx; }
    else          { base = kb; rel = idx - NQ; }
    int d4 = (rel & 15) * 4;
    int s = (rel >> 4) & 1023;
    int head = rel >> 14;
    bf16* p = base + ((size_t)head * Sn + s) * HDn + d4;
    ushort4 a = *reinterpret_cast<ushort4*>(p);
    ushort4 b = *reinterpret_cast<ushort4*>(p + 64);
    float4 c = *reinterpret_cast<const float4*>(&cosp[s * HDn + d4]);
    float4 sv = *reinterpret_cast<const float4*>(&sinp[s * HDn + d4]);
    float x1[4] = {__bfloat162float(__builtin_bit_cast(bf16, a.x)), __bfloat162float(__builtin_bit_cast(bf16, a.y)),
                   __bfloat162float(__builtin_bit_cast(bf16, a.z)), __bfloat162float(__builtin_bit_cast(bf16, a.w))};
    float x2[4] = {__bfloat162float(__builtin_bit_cast(bf16, b.x)), __bfloat162float(__builtin_bit_cast(bf16, b.y)),
                   __bfloat162float(__builtin_bit_cast(bf16, b.z)), __bfloat162float(__builtin_bit_cast(bf16, b.w))};
    float cc[4] = {c.x, c.y, c.z, c.w};
    float ss[4] = {sv.x, sv.y, sv.z, sv.w};
    ushort4 o1, o2;
    unsigned short* o1p = &o1.x; unsigned short* o2p = &o2.x;
    #pragma unroll
    for (int j = 0; j < 4; ++j) {
      o1p[j] = f2b_bits(x1[j] * cc[j] - x2[j] * ss[j]);
      o2p[j] = f2b_bits(x2[j] * cc[j] + x1[j] * ss[j]);
    }
    *reinterpret_cast<ushort4*>(p) = o1;
    *reinterpret_cast<ushort4*>(p + 64) = o2;
  }
}

// ---------------- fused flash attention, LDS-staged K/V (swizzled), 2-phase dbuf ----------------
__global__ __launch_bounds__(256) void attn_fwd(
    const bf16* __restrict__ q, const bf16* __restrict__ k, const bf16* __restrict__ vT,
    const unsigned char* __restrict__ m8, bf16* __restrict__ out) {
  __shared__ __align__(16) bf16 Kl[2][64 * 128];
  __shared__ __align__(16) bf16 Vl[2][128 * 64];
  __shared__ __align__(16) bf16 Pl[4][16 * 72];
  const int tid = threadIdx.x;
  const int lane = tid & 63, w = tid >> 6;
  const int l16 = lane & 15, lg = lane >> 4;
  const int qx = blockIdx.x, h = blockIdx.y, b = blockIdx.z;
  const int NQT = Sn / 64;
  const int qt = (b == 1) ? (NQT - 1 - qx) : qx;
  const int hkv = h >> 2;
  const int q0 = qt * 64 + w * 16;
  const float sl2 = 0.08838834764831845f * 1.44269504088896f;

  const bf16* qp = q + ((size_t)(b * Hn + h) * Sn + q0) * HDn;
  const bf16* kp = k + (size_t)(b * HKVn + hkv) * Sn * HDn;
  const bf16* vp = vT + (size_t)(b * HKVn + hkv) * HDn * Sn;
  const unsigned char* mp = m8 + b * Sn;

  auto stage = [&](int buf, int kbase) {
    #pragma unroll
    for (int i = 0; i < 4; ++i) {
      int ci = i * 256 + w * 64 + lane;
      int kr = ci >> 4, kch = ci & 15;
      ASYNC_LD16(kp + (size_t)(kbase + kr) * HDn + ((kch ^ (kr & 7)) * 8),
                 &Kl[buf][(i * 256 + w * 64) * 8]);
      int vr = ci >> 3, vch = ci & 7;
      ASYNC_LD16(vp + (size_t)vr * Sn + kbase + ((vch ^ (vr & 7)) * 8),
                 &Vl[buf][(i * 256 + w * 64) * 8]);
    }
  };

  s8v qf[4];
  #pragma unroll
  for (int hc = 0; hc < 4; ++hc)
    qf[hc] = *reinterpret_cast<const s8v*>(qp + l16 * HDn + hc * 32 + lg * 8);

  float mrow[4], lrow[4];
  f4v o[8] = {};
  #pragma unroll
  for (int i = 0; i < 4; ++i) { mrow[i] = -1e30f; lrow[i] = 0.f; }

  stage(0, 0);
  __syncthreads();

  for (int kt = 0; kt <= qt; ++kt) {
    const int cur = kt & 1;
    const int kb = kt * 64;
    if (kt < qt) stage(cur ^ 1, kb + 64);

    f4v sc[4] = {};
    #pragma unroll
    for (int ktc = 0; ktc < 4; ++ktc) {
      #pragma unroll
      for (int hc = 0; hc < 4; ++hc) {
        int r = ktc * 16 + l16;
        s8v kf = *reinterpret_cast<const s8v*>(
            &Kl[cur][r * 128 + (((hc * 4 + lg) ^ (r & 7)) * 8)]);
        sc[ktc] = __builtin_amdgcn_mfma_f32_16x16x32_bf16(qf[hc], kf, sc[ktc], 0, 0, 0);
      }
    }
    float pm[4];
    #pragma unroll
    for (int i = 0; i < 4; ++i) pm[i] = -1e30f;
    int act[4];
    #pragma unroll
    for (int ktc = 0; ktc < 4; ++ktc) act[ktc] = mp[kb + ktc * 16 + l16];
    if (kt == qt) {
      #pragma unroll
      for (int ktc = 0; ktc < 4; ++ktc) {
        int j = kb + ktc * 16 + l16;
        #pragma unroll
        for (int i = 0; i < 4; ++i) {
          int qr = q0 + lg * 4 + i;
          float v = sc[ktc][i] * sl2;
          v = (act[ktc] && j <= qr) ? v : -1e30f;
          sc[ktc][i] = v;
          pm[i] = fmaxf(pm[i], v);
        }
      }
    } else {
      #pragma unroll
      for (int ktc = 0; ktc < 4; ++ktc) {
        #pragma unroll
        for (int i = 0; i < 4; ++i) {
          float v = sc[ktc][i] * sl2;
          v = act[ktc] ? v : -1e30f;
          sc[ktc][i] = v;
          pm[i] = fmaxf(pm[i], v);
        }
      }
    }
    #pragma unroll
    for (int off = 1; off < 16; off <<= 1)
      #pragma unroll
      for (int i = 0; i < 4; ++i) pm[i] = fmaxf(pm[i], __shfl_xor(pm[i], off, 64));
    float fac[4];
    #pragma unroll
    for (int i = 0; i < 4; ++i) {
      float mn = fmaxf(mrow[i], pm[i]);
      fac[i] = exp2f(mrow[i] - mn);
      mrow[i] = mn;
    }
    float rs[4] = {0.f, 0.f, 0.f, 0.f};
    #pragma unroll
    for (int ktc = 0; ktc < 4; ++ktc)
      #pragma unroll
      for (int i = 0; i < 4; ++i) {
        float p = exp2f(sc[ktc][i] - mrow[i]);
        rs[i] += p;
        Pl[w][(lg * 4 + i) * 72 + ktc * 16 + l16] = __float2bfloat16(p);
      }
    #pragma unroll
    for (int off = 1; off < 16; off <<= 1)
      #pragma unroll
      for (int i = 0; i < 4; ++i) rs[i] += __shfl_xor(rs[i], off, 64);
    #pragma unroll
    for (int i = 0; i < 4; ++i) lrow[i] = lrow[i] * fac[i] + rs[i];
    #pragma unroll
    for (int fn = 0; fn < 8; ++fn)
      #pragma unroll
      for (int i = 0; i < 4; ++i) o[fn][i] *= fac[i];
    #pragma unroll
    for (int kc = 0; kc < 2; ++kc) {
      s8v pf = *reinterpret_cast<const s8v*>(&Pl[w][l16 * 72 + kc * 32 + lg * 8]);
      #pragma unroll
      for (int fn = 0; fn < 8; ++fn) {
        int d = fn * 16 + l16;
        s8v vf = *reinterpret_cast<const s8v*>(
            &Vl[cur][d * 64 + (((kc * 4 + lg) ^ (d & 7)) * 8)]);
        o[fn] = __builtin_amdgcn_mfma_f32_16x16x32_bf16(pf, vf, o[fn], 0, 0, 0);
      }
    }
    __syncthreads();
  }
  #pragma unroll
  for (int fn = 0; fn < 8; ++fn)
    #pragma unroll
    for (int i = 0; i < 4; ++i) {
      int qr = q0 + lg * 4 + i;
      out[((size_t)b * Sn + qr) * (Hn * HDn) + h * HDn + fn * 16 + l16] =
          __float2bfloat16(o[fn][i] / lrow[i]);
    }
}

extern "C" void kernel_launch(void* const* d_in, const int* in_sizes, int n_in,
                              void* d_out, int out_size, void* d_ws, size_t ws_size,
                              hipStream_t stream) {
  const float* hs   = (const float*)d_in[0];
  const float* cosp = (const float*)d_in[1];
  const float* sinp = (const float*)d_in[2];
  const float* wq   = (const float*)d_in[3];
  const float* wk   = (const float*)d_in[4];
  const float* wv   = (const float*)d_in[5];
  const float* wo   = (const float*)d_in[6];
  const void*  am   = d_in[8];

  char* ws = (char*)d_ws;
  bf16* WT  = (bf16*)(ws);
  bf16* woT = (bf16*)(ws + 12582912);
  bf16* qb  = (bf16*)(ws + 12582912 + 8388608);
  bf16* kb  = (bf16*)(ws + 12582912 + 16777216);
  bf16* vT  = (bf16*)(ws + 12582912 + 18874368);
  bf16* ao  = (bf16*)(ws + 12582912 + 20971520);
  unsigned char* m8 = (unsigned char*)(ws + 12582912 + 29360128);
  bf16* hsb = (bf16*)d_out;
  float* outp = (float*)d_out;

  mask_norm<<<1, 256, 0, stream>>>(am, m8, Bn * Sn);
  cvt_bf16<<<2048, 256, 0, stream>>>(hs, hsb, (Bn * Sn * Dn) / 8);
  transpose_all<<<dim3(32, 32, 4), 256, 0, stream>>>(
      wq, wk, wv, wo, WT, WT + (size_t)2048 * Dn, WT + (size_t)2560 * Dn, woT);
  gemm_nt<0><<<384, 256, 0, stream>>>(hsb, WT, qb, kb, vT, nullptr, Dn, 3072, 24);
  rope_qk<<<1024, 256, 0, stream>>>(qb, kb, cosp, sinp);
  attn_fwd<<<dim3(Sn / 64, Hn, Bn), 256, 0, stream>>>(qb, kb, vT, m8, ao);
  gemm_nt<1><<<256, 256, 0, stream>>>(ao, woT, nullptr, nullptr, nullptr, outp, Hn * HDn, Dn, 16);
}

// Round 9
// 233.568 us; speedup vs baseline: 1.4880x; 1.0194x over previous
//
#include <hip/hip_runtime.h>
#include <hip/hip_bf16.h>

#define Bn 2
#define Sn 1024
#define Dn 2048
#define Hn 16
#define HKVn 4
#define HDn 128

typedef __attribute__((ext_vector_type(8))) short s8v;
typedef __attribute__((ext_vector_type(8))) unsigned short u8v;
typedef __attribute__((ext_vector_type(4))) float f4v;
typedef __hip_bfloat16 bf16;

typedef __attribute__((address_space(3))) void lds_void;
typedef __attribute__((address_space(1))) const void gbl_void;
#define ASYNC_LD16(g, l) \
  __builtin_amdgcn_global_load_lds((gbl_void*)(g), (lds_void*)(l), 16, 0, 0)

static __device__ __forceinline__ unsigned short f2b_bits(float f) {
  bf16 h = __float2bfloat16(f);
  return __builtin_bit_cast(unsigned short, h);
}
static __device__ __forceinline__ float b2f(short u) {
  return __bfloat162float(__builtin_bit_cast(bf16, (unsigned short)u));
}

// ---------------- fused prep: cvt (blocks 0..1023), transposes (1024..3583), mask (3584) ----
// transpose jobs: wq 1024..2047, wk 2048..2303, wv 2304..2559, wo 2560..3583
__global__ __launch_bounds__(256) void prep(
    const float* __restrict__ hs, bf16* __restrict__ hsb,
    const float* __restrict__ wq, const float* __restrict__ wk,
    const float* __restrict__ wv, const float* __restrict__ wo,
    bf16* __restrict__ WT, bf16* __restrict__ woT,
    const void* __restrict__ am, unsigned char* __restrict__ m8) {
  const int bid = blockIdx.x;
  const int t = threadIdx.x;
  if (bid < 1024) {
    // fp32 -> bf16 convert, 8 elems/thread/iter, 2 iters
    const int n8 = (Bn * Sn * Dn) / 8;
    for (int i = bid * 256 + t; i < n8; i += 1024 * 256) {
      float4 a = reinterpret_cast<const float4*>(hs)[2 * i];
      float4 b = reinterpret_cast<const float4*>(hs)[2 * i + 1];
      u8v o;
      o[0] = f2b_bits(a.x); o[1] = f2b_bits(a.y); o[2] = f2b_bits(a.z); o[3] = f2b_bits(a.w);
      o[4] = f2b_bits(b.x); o[5] = f2b_bits(b.y); o[6] = f2b_bits(b.z); o[7] = f2b_bits(b.w);
      reinterpret_cast<u8v*>(hsb)[i] = o;
    }
    return;
  }
  if (bid == 3584) {
    // mask normalize (detect int32 vs byte bool)
    __shared__ int bytemode;
    if (t == 0) bytemode = 0;
    __syncthreads();
    const int n = Bn * Sn;
    const unsigned int* mi = (const unsigned int*)am;
    int local = 0;
    for (int i = t; i < n / 4; i += 256)
      if (mi[i] > 1u) local = 1;
    if (local) atomicOr(&bytemode, 1);
    __syncthreads();
    const int bm = bytemode;
    const unsigned char* mb = (const unsigned char*)am;
    for (int i = t; i < n; i += 256)
      m8[i] = bm ? (mb[i] ? 1 : 0) : (mi[i] != 0u ? 1 : 0);
    return;
  }
  // transposes: fp32 (K,N) -> bf16 (N,K), 64x64 tiles
  __shared__ float tile[64][65];
  const float* src;
  bf16* dst;
  int N, local;
  if (bid < 2048)      { src = wq; dst = WT;                          N = 2048; local = bid - 1024; }
  else if (bid < 2304) { src = wk; dst = WT + (size_t)2048 * Dn;      N = 512;  local = bid - 2048; }
  else if (bid < 2560) { src = wv; dst = WT + (size_t)2560 * Dn;      N = 512;  local = bid - 2304; }
  else                 { src = wo; dst = woT;                         N = 2048; local = bid - 2560; }
  const int nbx = N / 64;
  const int bx = (local % nbx) * 64;  // n
  const int by = (local / nbx) * 64;  // k
  const int lr = t >> 4, lc4 = (t & 15) * 4;
  #pragma unroll
  for (int it = 0; it < 4; ++it) {
    int k = it * 16 + lr;
    float4 v = *reinterpret_cast<const float4*>(&src[(size_t)(by + k) * N + bx + lc4]);
    tile[k][lc4] = v.x; tile[k][lc4 + 1] = v.y; tile[k][lc4 + 2] = v.z; tile[k][lc4 + 3] = v.w;
  }
  __syncthreads();
  #pragma unroll
  for (int it = 0; it < 4; ++it) {
    int n = it * 16 + lr;
    ushort4 o;
    o.x = f2b_bits(tile[lc4 + 0][n]);
    o.y = f2b_bits(tile[lc4 + 1][n]);
    o.z = f2b_bits(tile[lc4 + 2][n]);
    o.w = f2b_bits(tile[lc4 + 3][n]);
    *reinterpret_cast<ushort4*>(&dst[(size_t)(bx + n) * Dn + by + lc4]) = o;
  }
}

// ---------------- NT GEMM: global_load_lds + XOR swizzle + 2-phase double buffer ----------------
// Tile [128 rows][64 k] bf16 per operand: 8 chunks(16B)/row, chunk' = chunk ^ (row&7).
// 1D grid with bijective XCD swizzle (gridDim.x % 8 == 0).
// EPI 0: scatter to q (B,H,S,HD), k (B,HKV,S,HD), vT (B,HKV,HD,S)
// EPI 1: write fp32 C row-major
template <int EPI>
__global__ __launch_bounds__(256) void gemm_nt(
    const bf16* __restrict__ A, const bf16* __restrict__ Bt,
    bf16* __restrict__ Oq, bf16* __restrict__ Ok, bf16* __restrict__ Ov,
    float* __restrict__ Of, int K, int N, int nbx) {
  __shared__ __align__(16) bf16 Al[2][128 * 64];
  __shared__ __align__(16) bf16 Bl[2][128 * 64];
  const int tid = threadIdx.x;
  const int lane = tid & 63, w = tid >> 6;
  const int wm = (w >> 1) * 64, wn = (w & 1) * 64;
  const int nwg = gridDim.x;
  const int flat = blockIdx.x;
  const int swz = (flat & 7) * (nwg >> 3) + (flat >> 3);
  const int m0 = (swz / nbx) * 128, n0 = (swz % nbx) * 128;
  const int l16 = lane & 15, lg = lane >> 4;
  const int srow = lane >> 3;        // 0..7 row within 8-row chunk group
  const int sch = lane & 7;          // chunk within row
  f4v acc[4][4] = {};
  const int nt = K >> 6;

  auto stage = [&](int buf, int k0) {
    #pragma unroll
    for (int i = 0; i < 4; ++i) {
      const int rb = w * 32 + i * 8;          // wave-uniform base row
      const int r = rb + srow;
      const int cs = (sch ^ (r & 7)) * 8;     // pre-swizzled source column
      ASYNC_LD16(&A[(size_t)(m0 + r) * K + k0 + cs], &Al[buf][rb * 64]);
      ASYNC_LD16(&Bt[(size_t)(n0 + r) * K + k0 + cs], &Bl[buf][rb * 64]);
    }
  };

  stage(0, 0);
  __syncthreads();  // implicit vmcnt(0) drain

  for (int t = 0; t < nt; ++t) {
    const int cur = t & 1;
    if (t + 1 < nt) stage(cur ^ 1, (t + 1) << 6);  // prefetch overlaps compute
    #pragma unroll
    for (int kc = 0; kc < 2; ++kc) {
      s8v af[4], bfr[4];
      #pragma unroll
      for (int mf = 0; mf < 4; ++mf) {
        int r = wm + mf * 16 + l16;
        af[mf] = *reinterpret_cast<const s8v*>(&Al[cur][r * 64 + (((kc * 4 + lg) ^ (r & 7)) * 8)]);
      }
      #pragma unroll
      for (int nf = 0; nf < 4; ++nf) {
        int r = wn + nf * 16 + l16;
        bfr[nf] = *reinterpret_cast<const s8v*>(&Bl[cur][r * 64 + (((kc * 4 + lg) ^ (r & 7)) * 8)]);
      }
      #pragma unroll
      for (int mf = 0; mf < 4; ++mf)
        #pragma unroll
        for (int nf = 0; nf < 4; ++nf)
          acc[mf][nf] = __builtin_amdgcn_mfma_f32_16x16x32_bf16(af[mf], bfr[nf], acc[mf][nf], 0, 0, 0);
    }
    __syncthreads();  // drains prefetch (vmcnt 0) + protects both buffers
  }
  #pragma unroll
  for (int mf = 0; mf < 4; ++mf) {
    #pragma unroll
    for (int nf = 0; nf < 4; ++nf) {
      #pragma unroll
      for (int i = 0; i < 4; ++i) {
        int gm = m0 + wm + mf * 16 + lg * 4 + i;
        int gn = n0 + wn + nf * 16 + l16;
        float v = acc[mf][nf][i];
        if (EPI == 0) {
          int b = gm >> 10, s = gm & 1023;
          if (gn < 2048) {
            int h = gn >> 7, hd = gn & 127;
            Oq[(((size_t)(b * Hn + h)) * Sn + s) * HDn + hd] = __float2bfloat16(v);
          } else if (gn < 2560) {
            int t2 = gn - 2048, kvh = t2 >> 7, hd = t2 & 127;
            Ok[(((size_t)(b * HKVn + kvh)) * Sn + s) * HDn + hd] = __float2bfloat16(v);
          } else {
            int t2 = gn - 2560, kvh = t2 >> 7, hd = t2 & 127;
            Ov[(((size_t)(b * HKVn + kvh)) * HDn + hd) * Sn + s] = __float2bfloat16(v);
          }
        } else {
          Of[(size_t)gm * N + gn] = v;
        }
      }
    }
  }
}

// ---------------- RoPE in-place on K only, vectorized x4 ----------------
__global__ void rope_k(bf16* __restrict__ kb,
                       const float* __restrict__ cosp, const float* __restrict__ sinp) {
  const int NT = Bn * HKVn * Sn * 16;  // quads
  int idx = blockIdx.x * blockDim.x + threadIdx.x;
  if (idx >= NT) return;
  int d4 = (idx & 15) * 4;
  int s = (idx >> 4) & 1023;
  int head = idx >> 14;
  bf16* p = kb + ((size_t)head * Sn + s) * HDn + d4;
  ushort4 a = *reinterpret_cast<ushort4*>(p);
  ushort4 b = *reinterpret_cast<ushort4*>(p + 64);
  float4 c = *reinterpret_cast<const float4*>(&cosp[s * HDn + d4]);
  float4 sv = *reinterpret_cast<const float4*>(&sinp[s * HDn + d4]);
  float x1[4] = {b2f((short)a.x), b2f((short)a.y), b2f((short)a.z), b2f((short)a.w)};
  float x2[4] = {b2f((short)b.x), b2f((short)b.y), b2f((short)b.z), b2f((short)b.w)};
  float cc[4] = {c.x, c.y, c.z, c.w};
  float ss[4] = {sv.x, sv.y, sv.z, sv.w};
  ushort4 o1, o2;
  unsigned short* o1p = &o1.x; unsigned short* o2p = &o2.x;
  #pragma unroll
  for (int j = 0; j < 4; ++j) {
    o1p[j] = f2b_bits(x1[j] * cc[j] - x2[j] * ss[j]);
    o2p[j] = f2b_bits(x2[j] * cc[j] + x1[j] * ss[j]);
  }
  *reinterpret_cast<ushort4*>(p) = o1;
  *reinterpret_cast<ushort4*>(p + 64) = o2;
}

// ---------------- fused flash attention (Q-rope fused), LDS K/V swizzled, dbuf ----------------
__global__ __launch_bounds__(256) void attn_fwd(
    const bf16* __restrict__ q, const bf16* __restrict__ k, const bf16* __restrict__ vT,
    const unsigned char* __restrict__ m8, bf16* __restrict__ out,
    const float* __restrict__ cosp, const float* __restrict__ sinp) {
  __shared__ __align__(16) bf16 Kl[2][64 * 128];
  __shared__ __align__(16) bf16 Vl[2][128 * 64];
  __shared__ __align__(16) bf16 Pl[4][16 * 72];
  const int tid = threadIdx.x;
  const int lane = tid & 63, w = tid >> 6;
  const int l16 = lane & 15, lg = lane >> 4;
  const int qx = blockIdx.x, h = blockIdx.y, b = blockIdx.z;
  const int NQT = Sn / 64;
  const int qt = (b == 1) ? (NQT - 1 - qx) : qx;
  const int hkv = h >> 2;
  const int q0 = qt * 64 + w * 16;
  const float sl2 = 0.08838834764831845f * 1.44269504088896f;

  const bf16* qp = q + ((size_t)(b * Hn + h) * Sn + q0) * HDn;
  const bf16* kp = k + (size_t)(b * HKVn + hkv) * Sn * HDn;
  const bf16* vp = vT + (size_t)(b * HKVn + hkv) * HDn * Sn;
  const unsigned char* mp = m8 + b * Sn;

  auto stage = [&](int buf, int kbase) {
    #pragma unroll
    for (int i = 0; i < 4; ++i) {
      int ci = i * 256 + w * 64 + lane;
      int kr = ci >> 4, kch = ci & 15;
      ASYNC_LD16(kp + (size_t)(kbase + kr) * HDn + ((kch ^ (kr & 7)) * 8),
                 &Kl[buf][(i * 256 + w * 64) * 8]);
      int vr = ci >> 3, vch = ci & 7;
      ASYNC_LD16(vp + (size_t)vr * Sn + kbase + ((vch ^ (vr & 7)) * 8),
                 &Vl[buf][(i * 256 + w * 64) * 8]);
    }
  };

  // load Q fragments and apply RoPE in-register.
  // Fragment hc holds d = hc*32 + lg*8 + e; pair (d, d+64) lives in (hc, hc+2)
  // of the SAME lane; cos[d] == cos[d+64] (emb = concat(freqs, freqs)).
  s8v qf[4];
  {
    s8v qraw[4];
    #pragma unroll
    for (int hc = 0; hc < 4; ++hc)
      qraw[hc] = *reinterpret_cast<const s8v*>(qp + l16 * HDn + hc * 32 + lg * 8);
    const float* cb = cosp + (size_t)(q0 + l16) * HDn;
    const float* sb = sinp + (size_t)(q0 + l16) * HDn;
    #pragma unroll
    for (int hc = 0; hc < 2; ++hc) {
      #pragma unroll
      for (int jj = 0; jj < 2; ++jj) {
        float4 c4 = *reinterpret_cast<const float4*>(cb + hc * 32 + lg * 8 + jj * 4);
        float4 s4 = *reinterpret_cast<const float4*>(sb + hc * 32 + lg * 8 + jj * 4);
        float cc[4] = {c4.x, c4.y, c4.z, c4.w};
        float ss[4] = {s4.x, s4.y, s4.z, s4.w};
        #pragma unroll
        for (int j = 0; j < 4; ++j) {
          int e = jj * 4 + j;
          float lo = b2f(qraw[hc][e]);
          float hi = b2f(qraw[hc + 2][e]);
          qf[hc][e]     = (short)f2b_bits(lo * cc[j] - hi * ss[j]);
          qf[hc + 2][e] = (short)f2b_bits(hi * cc[j] + lo * ss[j]);
        }
      }
    }
  }

  float mrow[4], lrow[4];
  f4v o[8] = {};
  #pragma unroll
  for (int i = 0; i < 4; ++i) { mrow[i] = -1e30f; lrow[i] = 0.f; }

  stage(0, 0);
  __syncthreads();

  for (int kt = 0; kt <= qt; ++kt) {
    const int cur = kt & 1;
    const int kb = kt * 64;
    if (kt < qt) stage(cur ^ 1, kb + 64);

    f4v sc[4] = {};
    #pragma unroll
    for (int ktc = 0; ktc < 4; ++ktc) {
      #pragma unroll
      for (int hc = 0; hc < 4; ++hc) {
        int r = ktc * 16 + l16;
        s8v kf = *reinterpret_cast<const s8v*>(
            &Kl[cur][r * 128 + (((hc * 4 + lg) ^ (r & 7)) * 8)]);
        sc[ktc] = __builtin_amdgcn_mfma_f32_16x16x32_bf16(qf[hc], kf, sc[ktc], 0, 0, 0);
      }
    }
    float pm[4];
    #pragma unroll
    for (int i = 0; i < 4; ++i) pm[i] = -1e30f;
    int act[4];
    #pragma unroll
    for (int ktc = 0; ktc < 4; ++ktc) act[ktc] = mp[kb + ktc * 16 + l16];
    if (kt == qt) {
      #pragma unroll
      for (int ktc = 0; ktc < 4; ++ktc) {
        int j = kb + ktc * 16 + l16;
        #pragma unroll
        for (int i = 0; i < 4; ++i) {
          int qr = q0 + lg * 4 + i;
          float v = sc[ktc][i] * sl2;
          v = (act[ktc] && j <= qr) ? v : -1e30f;
          sc[ktc][i] = v;
          pm[i] = fmaxf(pm[i], v);
        }
      }
    } else {
      #pragma unroll
      for (int ktc = 0; ktc < 4; ++ktc) {
        #pragma unroll
        for (int i = 0; i < 4; ++i) {
          float v = sc[ktc][i] * sl2;
          v = act[ktc] ? v : -1e30f;
          sc[ktc][i] = v;
          pm[i] = fmaxf(pm[i], v);
        }
      }
    }
    #pragma unroll
    for (int off = 1; off < 16; off <<= 1)
      #pragma unroll
      for (int i = 0; i < 4; ++i) pm[i] = fmaxf(pm[i], __shfl_xor(pm[i], off, 64));
    float fac[4];
    #pragma unroll
    for (int i = 0; i < 4; ++i) {
      float mn = fmaxf(mrow[i], pm[i]);
      fac[i] = exp2f(mrow[i] - mn);
      mrow[i] = mn;
    }
    float rs[4] = {0.f, 0.f, 0.f, 0.f};
    #pragma unroll
    for (int ktc = 0; ktc < 4; ++ktc)
      #pragma unroll
      for (int i = 0; i < 4; ++i) {
        float p = exp2f(sc[ktc][i] - mrow[i]);
        rs[i] += p;
        Pl[w][(lg * 4 + i) * 72 + ktc * 16 + l16] = __float2bfloat16(p);
      }
    #pragma unroll
    for (int off = 1; off < 16; off <<= 1)
      #pragma unroll
      for (int i = 0; i < 4; ++i) rs[i] += __shfl_xor(rs[i], off, 64);
    #pragma unroll
    for (int i = 0; i < 4; ++i) lrow[i] = lrow[i] * fac[i] + rs[i];
    #pragma unroll
    for (int fn = 0; fn < 8; ++fn)
      #pragma unroll
      for (int i = 0; i < 4; ++i) o[fn][i] *= fac[i];
    #pragma unroll
    for (int kc = 0; kc < 2; ++kc) {
      s8v pf = *reinterpret_cast<const s8v*>(&Pl[w][l16 * 72 + kc * 32 + lg * 8]);
      #pragma unroll
      for (int fn = 0; fn < 8; ++fn) {
        int d = fn * 16 + l16;
        s8v vf = *reinterpret_cast<const s8v*>(
            &Vl[cur][d * 64 + (((kc * 4 + lg) ^ (d & 7)) * 8)]);
        o[fn] = __builtin_amdgcn_mfma_f32_16x16x32_bf16(pf, vf, o[fn], 0, 0, 0);
      }
    }
    __syncthreads();
  }
  #pragma unroll
  for (int fn = 0; fn < 8; ++fn)
    #pragma unroll
    for (int i = 0; i < 4; ++i) {
      int qr = q0 + lg * 4 + i;
      out[((size_t)b * Sn + qr) * (Hn * HDn) + h * HDn + fn * 16 + l16] =
          __float2bfloat16(o[fn][i] / lrow[i]);
    }
}

extern "C" void kernel_launch(void* const* d_in, const int* in_sizes, int n_in,
                              void* d_out, int out_size, void* d_ws, size_t ws_size,
                              hipStream_t stream) {
  const float* hs   = (const float*)d_in[0];
  const float* cosp = (const float*)d_in[1];
  const float* sinp = (const float*)d_in[2];
  const float* wq   = (const float*)d_in[3];
  const float* wk   = (const float*)d_in[4];
  const float* wv   = (const float*)d_in[5];
  const float* wo   = (const float*)d_in[6];
  const void*  am   = d_in[8];

  char* ws = (char*)d_ws;
  bf16* WT  = (bf16*)(ws);
  bf16* woT = (bf16*)(ws + 12582912);
  bf16* qb  = (bf16*)(ws + 12582912 + 8388608);
  bf16* kb  = (bf16*)(ws + 12582912 + 16777216);
  bf16* vT  = (bf16*)(ws + 12582912 + 18874368);
  bf16* ao  = (bf16*)(ws + 12582912 + 20971520);
  unsigned char* m8 = (unsigned char*)(ws + 12582912 + 29360128);
  bf16* hsb = (bf16*)d_out;
  float* outp = (float*)d_out;

  prep<<<3585, 256, 0, stream>>>(hs, hsb, wq, wk, wv, wo, WT, woT, am, m8);
  gemm_nt<0><<<384, 256, 0, stream>>>(hsb, WT, qb, kb, vT, nullptr, Dn, 3072, 24);
  rope_k<<<512, 256, 0, stream>>>(kb, cosp, sinp);
  attn_fwd<<<dim3(Sn / 64, Hn, Bn), 256, 0, stream>>>(qb, kb, vT, m8, ao, cosp, sinp);
  gemm_nt<1><<<256, 256, 0, stream>>>(ao, woT, nullptr, nullptr, nullptr, outp, Hn * HDn, Dn, 16);
}

// Round 11
// 214.412 us; speedup vs baseline: 1.6209x; 1.0893x over previous
//
#include <hip/hip_runtime.h>
#include <hip/hip_bf16.h>

#define Bn 2
#define Sn 1024
#define Dn 2048
#define Hn 16
#define HKVn 4
#define HDn 128

typedef __attribute__((ext_vector_type(8))) short s8v;
typedef __attribute__((ext_vector_type(8))) unsigned short u8v;
typedef __attribute__((ext_vector_type(4))) float f4v;
typedef __hip_bfloat16 bf16;

typedef __attribute__((address_space(3))) void lds_void;
typedef __attribute__((address_space(1))) const void gbl_void;
#define ASYNC_LD16(g, l) \
  __builtin_amdgcn_global_load_lds((gbl_void*)(g), (lds_void*)(l), 16, 0, 0)

static __device__ __forceinline__ unsigned short f2b_bits(float f) {
  bf16 h = __float2bfloat16(f);
  return __builtin_bit_cast(unsigned short, h);
}
static __device__ __forceinline__ float b2f(short u) {
  return __bfloat162float(__builtin_bit_cast(bf16, (unsigned short)u));
}

// ---------------- fused prep: cvt (blocks 0..1023), transposes (1024..3583), mask (3584) ----
__global__ __launch_bounds__(256) void prep(
    const float* __restrict__ hs, bf16* __restrict__ hsb,
    const float* __restrict__ wq, const float* __restrict__ wk,
    const float* __restrict__ wv, const float* __restrict__ wo,
    bf16* __restrict__ WT, bf16* __restrict__ woT,
    const void* __restrict__ am, unsigned char* __restrict__ m8) {
  const int bid = blockIdx.x;
  const int t = threadIdx.x;
  if (bid < 1024) {
    const int n8 = (Bn * Sn * Dn) / 8;
    for (int i = bid * 256 + t; i < n8; i += 1024 * 256) {
      float4 a = reinterpret_cast<const float4*>(hs)[2 * i];
      float4 b = reinterpret_cast<const float4*>(hs)[2 * i + 1];
      u8v o;
      o[0] = f2b_bits(a.x); o[1] = f2b_bits(a.y); o[2] = f2b_bits(a.z); o[3] = f2b_bits(a.w);
      o[4] = f2b_bits(b.x); o[5] = f2b_bits(b.y); o[6] = f2b_bits(b.z); o[7] = f2b_bits(b.w);
      reinterpret_cast<u8v*>(hsb)[i] = o;
    }
    return;
  }
  if (bid == 3584) {
    __shared__ int bytemode;
    if (t == 0) bytemode = 0;
    __syncthreads();
    const int n = Bn * Sn;
    const unsigned int* mi = (const unsigned int*)am;
    int local = 0;
    for (int i = t; i < n / 4; i += 256)
      if (mi[i] > 1u) local = 1;
    if (local) atomicOr(&bytemode, 1);
    __syncthreads();
    const int bm = bytemode;
    const unsigned char* mb = (const unsigned char*)am;
    for (int i = t; i < n; i += 256)
      m8[i] = bm ? (mb[i] ? 1 : 0) : (mi[i] != 0u ? 1 : 0);
    return;
  }
  __shared__ float tile[64][65];
  const float* src;
  bf16* dst;
  int N, local;
  if (bid < 2048)      { src = wq; dst = WT;                          N = 2048; local = bid - 1024; }
  else if (bid < 2304) { src = wk; dst = WT + (size_t)2048 * Dn;      N = 512;  local = bid - 2048; }
  else if (bid < 2560) { src = wv; dst = WT + (size_t)2560 * Dn;      N = 512;  local = bid - 2304; }
  else                 { src = wo; dst = woT;                         N = 2048; local = bid - 2560; }
  const int nbx = N / 64;
  const int bx = (local % nbx) * 64;
  const int by = (local / nbx) * 64;
  const int lr = t >> 4, lc4 = (t & 15) * 4;
  #pragma unroll
  for (int it = 0; it < 4; ++it) {
    int k = it * 16 + lr;
    float4 v = *reinterpret_cast<const float4*>(&src[(size_t)(by + k) * N + bx + lc4]);
    tile[k][lc4] = v.x; tile[k][lc4 + 1] = v.y; tile[k][lc4 + 2] = v.z; tile[k][lc4 + 3] = v.w;
  }
  __syncthreads();
  #pragma unroll
  for (int it = 0; it < 4; ++it) {
    int n = it * 16 + lr;
    ushort4 o;
    o.x = f2b_bits(tile[lc4 + 0][n]);
    o.y = f2b_bits(tile[lc4 + 1][n]);
    o.z = f2b_bits(tile[lc4 + 2][n]);
    o.w = f2b_bits(tile[lc4 + 3][n]);
    *reinterpret_cast<ushort4*>(&dst[(size_t)(bx + n) * Dn + by + lc4]) = o;
  }
}

// ---------------- NT GEMM: global_load_lds + XOR swizzle + dbuf; K-RoPE fused epilogue ------
// Tile [128 rows][64 k] bf16 per operand: 8 chunks(16B)/row, chunk' = chunk ^ (row&7).
// Staging LDS layout in SM: A buf0 @0, A buf1 @16384, B buf0 @32768, B buf1 @49152.
// EPI 0: scatter q / roped-k / vT. K-region tiles (n0 in [2048,2560)) cover exactly one
//        KV head's 128 cols; rope pair (col, col^64) exchanged via dead staging LDS (fp32).
// EPI 1: write fp32 C row-major.
template <int EPI>
__global__ __launch_bounds__(256) void gemm_nt(
    const bf16* __restrict__ A, const bf16* __restrict__ Bt,
    bf16* __restrict__ Oq, bf16* __restrict__ Ok, bf16* __restrict__ Ov,
    float* __restrict__ Of, const float* __restrict__ cosp, const float* __restrict__ sinp,
    int K, int N, int nbx) {
  __shared__ __align__(16) char SM[65536];
  const int tid = threadIdx.x;
  const int lane = tid & 63, w = tid >> 6;
  const int wm = (w >> 1) * 64, wn = (w & 1) * 64;
  const int nwg = gridDim.x;
  const int flat = blockIdx.x;
  const int swz = (flat & 7) * (nwg >> 3) + (flat >> 3);
  const int m0 = (swz / nbx) * 128, n0 = (swz % nbx) * 128;
  const int l16 = lane & 15, lg = lane >> 4;
  const int srow = lane >> 3;
  const int sch = lane & 7;
  f4v acc[4][4] = {};
  const int nt = K >> 6;

  auto stage = [&](int buf, int k0) {
    bf16* Ab = (bf16*)(SM + buf * 16384);
    bf16* Bb = (bf16*)(SM + 32768 + buf * 16384);
    #pragma unroll
    for (int i = 0; i < 4; ++i) {
      const int rb = w * 32 + i * 8;
      const int r = rb + srow;
      const int cs = (sch ^ (r & 7)) * 8;
      ASYNC_LD16(&A[(size_t)(m0 + r) * K + k0 + cs], &Ab[rb * 64]);
      ASYNC_LD16(&Bt[(size_t)(n0 + r) * K + k0 + cs], &Bb[rb * 64]);
    }
  };

  stage(0, 0);
  __syncthreads();

  for (int t = 0; t < nt; ++t) {
    const int cur = t & 1;
    if (t + 1 < nt) stage(cur ^ 1, (t + 1) << 6);
    const bf16* Ac = (const bf16*)(SM + cur * 16384);
    const bf16* Bc = (const bf16*)(SM + 32768 + cur * 16384);
    #pragma unroll
    for (int kc = 0; kc < 2; ++kc) {
      s8v af[4], bfr[4];
      #pragma unroll
      for (int mf = 0; mf < 4; ++mf) {
        int r = wm + mf * 16 + l16;
        af[mf] = *reinterpret_cast<const s8v*>(&Ac[r * 64 + (((kc * 4 + lg) ^ (r & 7)) * 8)]);
      }
      #pragma unroll
      for (int nf = 0; nf < 4; ++nf) {
        int r = wn + nf * 16 + l16;
        bfr[nf] = *reinterpret_cast<const s8v*>(&Bc[r * 64 + (((kc * 4 + lg) ^ (r & 7)) * 8)]);
      }
      #pragma unroll
      for (int mf = 0; mf < 4; ++mf)
        #pragma unroll
        for (int nf = 0; nf < 4; ++nf)
          acc[mf][nf] = __builtin_amdgcn_mfma_f32_16x16x32_bf16(af[mf], bfr[nf], acc[mf][nf], 0, 0, 0);
    }
    __syncthreads();
  }

  if (EPI == 0 && n0 >= 2048 && n0 < 2560) {
    // --- K region: fused RoPE via LDS fp32 exchange (staging buffers are dead) ---
    float* Cl = (float*)SM;  // [128][128] fp32 = 64 KB
    const int kvh = (n0 - 2048) >> 7;
    #pragma unroll
    for (int mf = 0; mf < 4; ++mf)
      #pragma unroll
      for (int nf = 0; nf < 4; ++nf)
        #pragma unroll
        for (int i = 0; i < 4; ++i)
          Cl[(wm + mf * 16 + lg * 4 + i) * 128 + wn + nf * 16 + l16] = acc[mf][nf][i];
    __syncthreads();
    #pragma unroll
    for (int mf = 0; mf < 4; ++mf) {
      #pragma unroll
      for (int nf = 0; nf < 4; ++nf) {
        #pragma unroll
        for (int i = 0; i < 4; ++i) {
          int row = wm + mf * 16 + lg * 4 + i;
          int col = wn + nf * 16 + l16;
          int gm = m0 + row, b = gm >> 10, s = gm & 1023;
          float x = Cl[row * 128 + col];
          float y = Cl[row * 128 + (col ^ 64)];
          float c = cosp[s * HDn + col];
          float sn = sinp[s * HDn + col];
          float v = (col < 64) ? (x * c - y * sn) : (x * c + y * sn);
          Ok[(((size_t)(b * HKVn + kvh)) * Sn + s) * HDn + col] = __float2bfloat16(v);
        }
      }
    }
    return;
  }
  #pragma unroll
  for (int mf = 0; mf < 4; ++mf) {
    #pragma unroll
    for (int nf = 0; nf < 4; ++nf) {
      #pragma unroll
      for (int i = 0; i < 4; ++i) {
        int gm = m0 + wm + mf * 16 + lg * 4 + i;
        int gn = n0 + wn + nf * 16 + l16;
        float v = acc[mf][nf][i];
        if (EPI == 0) {
          int b = gm >> 10, s = gm & 1023;
          if (gn < 2048) {
            int h = gn >> 7, hd = gn & 127;
            Oq[(((size_t)(b * Hn + h)) * Sn + s) * HDn + hd] = __float2bfloat16(v);
          } else {
            int t2 = gn - 2560, kvh = t2 >> 7, hd = t2 & 127;
            Ov[(((size_t)(b * HKVn + kvh)) * HDn + hd) * Sn + s] = __float2bfloat16(v);
          }
        } else {
          Of[(size_t)gm * N + gn] = v;
        }
      }
    }
  }
}

// ---------------- fused flash attention (Q-rope fused), LDS K/V swizzled, dbuf ----------------
__global__ __launch_bounds__(256) void attn_fwd(
    const bf16* __restrict__ q, const bf16* __restrict__ k, const bf16* __restrict__ vT,
    const unsigned char* __restrict__ m8, bf16* __restrict__ out,
    const float* __restrict__ cosp, const float* __restrict__ sinp) {
  __shared__ __align__(16) bf16 Kl[2][64 * 128];
  __shared__ __align__(16) bf16 Vl[2][128 * 64];
  __shared__ __align__(16) bf16 Pl[4][16 * 72];
  const int tid = threadIdx.x;
  const int lane = tid & 63, w = tid >> 6;
  const int l16 = lane & 15, lg = lane >> 4;
  const int qx = blockIdx.x, h = blockIdx.y, b = blockIdx.z;
  const int NQT = Sn / 64;
  const int qt = (b == 1) ? (NQT - 1 - qx) : qx;
  const int hkv = h >> 2;
  const int q0 = qt * 64 + w * 16;
  const float sl2 = 0.08838834764831845f * 1.44269504088896f;

  const bf16* qp = q + ((size_t)(b * Hn + h) * Sn + q0) * HDn;
  const bf16* kp = k + (size_t)(b * HKVn + hkv) * Sn * HDn;
  const bf16* vp = vT + (size_t)(b * HKVn + hkv) * HDn * Sn;
  const unsigned char* mp = m8 + b * Sn;

  auto stage = [&](int buf, int kbase) {
    #pragma unroll
    for (int i = 0; i < 4; ++i) {
      int ci = i * 256 + w * 64 + lane;
      int kr = ci >> 4, kch = ci & 15;
      ASYNC_LD16(kp + (size_t)(kbase + kr) * HDn + ((kch ^ (kr & 7)) * 8),
                 &Kl[buf][(i * 256 + w * 64) * 8]);
      int vr = ci >> 3, vch = ci & 7;
      ASYNC_LD16(vp + (size_t)vr * Sn + kbase + ((vch ^ (vr & 7)) * 8),
                 &Vl[buf][(i * 256 + w * 64) * 8]);
    }
  };

  s8v qf[4];
  {
    s8v qraw[4];
    #pragma unroll
    for (int hc = 0; hc < 4; ++hc)
      qraw[hc] = *reinterpret_cast<const s8v*>(qp + l16 * HDn + hc * 32 + lg * 8);
    const float* cb = cosp + (size_t)(q0 + l16) * HDn;
    const float* sb = sinp + (size_t)(q0 + l16) * HDn;
    #pragma unroll
    for (int hc = 0; hc < 2; ++hc) {
      #pragma unroll
      for (int jj = 0; jj < 2; ++jj) {
        float4 c4 = *reinterpret_cast<const float4*>(cb + hc * 32 + lg * 8 + jj * 4);
        float4 s4 = *reinterpret_cast<const float4*>(sb + hc * 32 + lg * 8 + jj * 4);
        float cc[4] = {c4.x, c4.y, c4.z, c4.w};
        float ss[4] = {s4.x, s4.y, s4.z, s4.w};
        #pragma unroll
        for (int j = 0; j < 4; ++j) {
          int e = jj * 4 + j;
          float lo = b2f(qraw[hc][e]);
          float hi = b2f(qraw[hc + 2][e]);
          qf[hc][e]     = (short)f2b_bits(lo * cc[j] - hi * ss[j]);
          qf[hc + 2][e] = (short)f2b_bits(hi * cc[j] + lo * ss[j]);
        }
      }
    }
  }

  float mrow[4], lrow[4];
  f4v o[8] = {};
  #pragma unroll
  for (int i = 0; i < 4; ++i) { mrow[i] = -1e30f; lrow[i] = 0.f; }

  stage(0, 0);
  __syncthreads();

  for (int kt = 0; kt <= qt; ++kt) {
    const int cur = kt & 1;
    const int kb = kt * 64;
    if (kt < qt) stage(cur ^ 1, kb + 64);

    f4v sc[4] = {};
    #pragma unroll
    for (int ktc = 0; ktc < 4; ++ktc) {
      #pragma unroll
      for (int hc = 0; hc < 4; ++hc) {
        int r = ktc * 16 + l16;
        s8v kf = *reinterpret_cast<const s8v*>(
            &Kl[cur][r * 128 + (((hc * 4 + lg) ^ (r & 7)) * 8)]);
        sc[ktc] = __builtin_amdgcn_mfma_f32_16x16x32_bf16(qf[hc], kf, sc[ktc], 0, 0, 0);
      }
    }
    float pm[4];
    #pragma unroll
    for (int i = 0; i < 4; ++i) pm[i] = -1e30f;
    int act[4];
    #pragma unroll
    for (int ktc = 0; ktc < 4; ++ktc) act[ktc] = mp[kb + ktc * 16 + l16];
    if (kt == qt) {
      #pragma unroll
      for (int ktc = 0; ktc < 4; ++ktc) {
        int j = kb + ktc * 16 + l16;
        #pragma unroll
        for (int i = 0; i < 4; ++i) {
          int qr = q0 + lg * 4 + i;
          float v = sc[ktc][i] * sl2;
          v = (act[ktc] && j <= qr) ? v : -1e30f;
          sc[ktc][i] = v;
          pm[i] = fmaxf(pm[i], v);
        }
      }
    } else {
      #pragma unroll
      for (int ktc = 0; ktc < 4; ++ktc) {
        #pragma unroll
        for (int i = 0; i < 4; ++i) {
          float v = sc[ktc][i] * sl2;
          v = act[ktc] ? v : -1e30f;
          sc[ktc][i] = v;
          pm[i] = fmaxf(pm[i], v);
        }
      }
    }
    #pragma unroll
    for (int off = 1; off < 16; off <<= 1)
      #pragma unroll
      for (int i = 0; i < 4; ++i) pm[i] = fmaxf(pm[i], __shfl_xor(pm[i], off, 64));
    float fac[4];
    #pragma unroll
    for (int i = 0; i < 4; ++i) {
      float mn = fmaxf(mrow[i], pm[i]);
      fac[i] = exp2f(mrow[i] - mn);
      mrow[i] = mn;
    }
    float rs[4] = {0.f, 0.f, 0.f, 0.f};
    #pragma unroll
    for (int ktc = 0; ktc < 4; ++ktc)
      #pragma unroll
      for (int i = 0; i < 4; ++i) {
        float p = exp2f(sc[ktc][i] - mrow[i]);
        rs[i] += p;
        Pl[w][(lg * 4 + i) * 72 + ktc * 16 + l16] = __float2bfloat16(p);
      }
    #pragma unroll
    for (int off = 1; off < 16; off <<= 1)
      #pragma unroll
      for (int i = 0; i < 4; ++i) rs[i] += __shfl_xor(rs[i], off, 64);
    #pragma unroll
    for (int i = 0; i < 4; ++i) lrow[i] = lrow[i] * fac[i] + rs[i];
    #pragma unroll
    for (int fn = 0; fn < 8; ++fn)
      #pragma unroll
      for (int i = 0; i < 4; ++i) o[fn][i] *= fac[i];
    #pragma unroll
    for (int kc = 0; kc < 2; ++kc) {
      s8v pf = *reinterpret_cast<const s8v*>(&Pl[w][l16 * 72 + kc * 32 + lg * 8]);
      #pragma unroll
      for (int fn = 0; fn < 8; ++fn) {
        int d = fn * 16 + l16;
        s8v vf = *reinterpret_cast<const s8v*>(
            &Vl[cur][d * 64 + (((kc * 4 + lg) ^ (d & 7)) * 8)]);
        o[fn] = __builtin_amdgcn_mfma_f32_16x16x32_bf16(pf, vf, o[fn], 0, 0, 0);
      }
    }
    __syncthreads();
  }
  #pragma unroll
  for (int fn = 0; fn < 8; ++fn)
    #pragma unroll
    for (int i = 0; i < 4; ++i) {
      int qr = q0 + lg * 4 + i;
      out[((size_t)b * Sn + qr) * (Hn * HDn) + h * HDn + fn * 16 + l16] =
          __float2bfloat16(o[fn][i] / lrow[i]);
    }
}

extern "C" void kernel_launch(void* const* d_in, const int* in_sizes, int n_in,
                              void* d_out, int out_size, void* d_ws, size_t ws_size,
                              hipStream_t stream) {
  const float* hs   = (const float*)d_in[0];
  const float* cosp = (const float*)d_in[1];
  const float* sinp = (const float*)d_in[2];
  const float* wq   = (const float*)d_in[3];
  const float* wk   = (const float*)d_in[4];
  const float* wv   = (const float*)d_in[5];
  const float* wo   = (const float*)d_in[6];
  const void*  am   = d_in[8];

  char* ws = (char*)d_ws;
  bf16* WT  = (bf16*)(ws);
  bf16* woT = (bf16*)(ws + 12582912);
  bf16* qb  = (bf16*)(ws + 12582912 + 8388608);
  bf16* kb  = (bf16*)(ws + 12582912 + 16777216);
  bf16* vT  = (bf16*)(ws + 12582912 + 18874368);
  bf16* ao  = (bf16*)(ws + 12582912 + 20971520);
  unsigned char* m8 = (unsigned char*)(ws + 12582912 + 29360128);
  bf16* hsb = (bf16*)d_out;
  float* outp = (float*)d_out;

  prep<<<3585, 256, 0, stream>>>(hs, hsb, wq, wk, wv, wo, WT, woT, am, m8);
  gemm_nt<0><<<384, 256, 0, stream>>>(hsb, WT, qb, kb, vT, nullptr, cosp, sinp, Dn, 3072, 24);
  attn_fwd<<<dim3(Sn / 64, Hn, Bn), 256, 0, stream>>>(qb, kb, vT, m8, ao, cosp, sinp);
  gemm_nt<1><<<256, 256, 0, stream>>>(ao, woT, nullptr, nullptr, nullptr, outp, nullptr, nullptr, Hn * HDn, Dn, 16);
}